// Round 7
// baseline (608.218 us; speedup 1.0000x reference)
//
#include <hip/hip_runtime.h>
#include <hip/hip_bf16.h>

#define HD 128
#define H 4
#define D 32
#define SLOTS 64

typedef __hip_bfloat16 bf16;
typedef __attribute__((ext_vector_type(8))) short bf16x8;
typedef __attribute__((ext_vector_type(4))) float f32x4;
typedef __attribute__((ext_vector_type(4))) short short4v;

__device__ __forceinline__ float bf2f(unsigned short u) {
    union { unsigned int i; float f; } v; v.i = ((unsigned int)u) << 16; return v.f;
}
__device__ __forceinline__ short f2bf(float f) {
    union { float f; unsigned u; } v; v.f = f;
    unsigned r = v.u + 0x7fff + ((v.u >> 16) & 1);
    return (short)(r >> 16);
}
// HW packed fp32->bf16 (RNE), 2 values/instr
__device__ __forceinline__ short4v pack4(float a0, float a1, float a2, float a3) {
    union { unsigned u[2]; short4v v; } r;
    asm("v_cvt_pk_bf16_f32 %0, %1, %2" : "=v"(r.u[0]) : "v"(a0), "v"(a1));
    asm("v_cvt_pk_bf16_f32 %0, %1, %2" : "=v"(r.u[1]) : "v"(a2), "v"(a3));
    return r.v;
}
__device__ __forceinline__ bf16x8 pack8(const f32x4 lo, const f32x4 hi) {
    union { unsigned u[4]; bf16x8 v; } r;
    asm("v_cvt_pk_bf16_f32 %0, %1, %2" : "=v"(r.u[0]) : "v"(lo[0]), "v"(lo[1]));
    asm("v_cvt_pk_bf16_f32 %0, %1, %2" : "=v"(r.u[1]) : "v"(lo[2]), "v"(lo[3]));
    asm("v_cvt_pk_bf16_f32 %0, %1, %2" : "=v"(r.u[2]) : "v"(hi[0]), "v"(hi[1]));
    asm("v_cvt_pk_bf16_f32 %0, %1, %2" : "=v"(r.u[3]) : "v"(hi[2]), "v"(hi[3]));
    return r.v;
}

// ---------------- weight pre-transpose: dst[b][c][kd] = bf16(src[b][k][c]) ----------------
__global__ __launch_bounds__(256) void transpose_bf16(
    const float* __restrict__ src, bf16* __restrict__ dst, int K, int C, int Kd, int total) {
    int i = blockIdx.x * 256 + threadIdx.x;
    if (i >= total) return;
    int kd = i % Kd; int rem = i / Kd; int c = rem % C; int b = rem / C;
    float v = (kd < K) ? src[((size_t)b * K + kd) * C + c] : 0.f;
    ((unsigned short*)dst)[i] = (unsigned short)f2bf(v);
}

// ---------------- fuse relation transforms into k/v weights ----------------
// Wall layout per layer: slot 0,1 = WqT(t0,t1); 2..4 = fused K rel0..2; 5..7 = fused V rel0..2
__global__ __launch_bounds__(256) void fuse_relw(
    const float* __restrict__ Wk, const float* __restrict__ Wv,
    const float* __restrict__ Krel, const float* __restrict__ Vrel,
    bf16* __restrict__ Wall) {
    int gid = blockIdx.x * 256 + threadIdx.x;  // 12 * 16384
    int m = gid >> 14;
    int idx = gid & 16383;
    int ep = idx >> 7, i = idx & 127;
    int l = m / 6, kv = (m / 3) & 1, r = m % 3;
    int s = (r == 0) ? 0 : 1;
    const float* W = (kv ? Wv : Wk) + ((size_t)(l * 2 + s)) * 16384;
    const float* R = (kv ? Vrel : Krel) + ((size_t)(l * 3 + r)) * 4096;
    int h = ep >> 5, e = ep & 31;
    float acc = 0.f;
#pragma unroll
    for (int d = 0; d < 32; ++d)
        acc = fmaf(W[i * 128 + h * 32 + d], R[h * 1024 + d * 32 + e], acc);
    int slot = l * 8 + 2 + kv * 3 + r;
    ((unsigned short*)Wall)[(size_t)slot * 16384 + ep * 128 + i] = (unsigned short)f2bf(acc);
}

// Ball layout per layer: [8][128] fp32; slots 0,1 = bq; 2..4 fused bk; 5..7 fused bv
__global__ __launch_bounds__(256) void fuse_relb(
    const float* __restrict__ bk, const float* __restrict__ bv, const float* __restrict__ bq,
    const float* __restrict__ Krel, const float* __restrict__ Vrel,
    float* __restrict__ Ball) {
    int gid = blockIdx.x * 256 + threadIdx.x;  // 2048
    if (gid >= 2048) return;
    int col = gid & 127, m = gid >> 7;
    int l = m >> 3, g = m & 7;
    float val;
    if (g < 2) {
        val = bq[(l * 2 + g) * 128 + col];
    } else {
        int kv = (g - 2) / 3, r = (g - 2) % 3, s = (r == 0) ? 0 : 1;
        const float* b = (kv ? bv : bk) + (size_t)(l * 2 + s) * 128;
        const float* R = (kv ? Vrel : Krel) + (size_t)(l * 3 + r) * 4096;
        int h = col >> 5, e = col & 31;
        float acc = 0.f;
#pragma unroll
        for (int d = 0; d < 32; ++d)
            acc = fmaf(b[h * 32 + d], R[h * 1024 + d * 32 + e], acc);
        val = acc;
    }
    Ball[gid] = val;
}

// ---------------- adjacency build: fixed 64 slots per dst node ----------------
__global__ __launch_bounds__(256) void build_adj(
    const int* __restrict__ edge, int* __restrict__ adj, int* __restrict__ deg,
    int dstBase, int rel, int E) {
    int i = blockIdx.x * 256 + threadIdx.x;
    if (i >= E) return;
    int src = edge[i];
    int dst = edge[E + i];
    int slot = atomicAdd(deg + dstBase + dst, 1);
    if (slot < SLOTS) adj[(size_t)(dstBase + dst) * SLOTS + slot] = src | (rel << 20);
}

// ---------------- MFMA 16x16x32, A=weightT (outcol rows), B=X^T (node cols) ----------------
// A-frag: lane holds A[row=l&15][k=(l>>4)*8+j]  -> row indexes OUTPUT COLUMN
// B-frag: lane holds B[k=(l>>4)*8+j][col=l&15]  -> col indexes NODE; element = X[node][k]
// D:      lane reg j = D[outcol=(l>>4)*4+j (+tile)][node=l&15]

// ---------------- shared qkv slice phase: reads X tile from LDS ----------------
// type 0 -> slices {0,2,5}; type 1 -> {1,3,4,6,7}. Wave w owns outcols [w*32, w*32+32).
// OUTPUT: q slices (g<2) -> q[g][node][128]; K/V slices -> kv[r][node][512B record: K|V]
// Round-4 structure (verified best). NO launch-bounds clamp (r1/r2: 64-VGPR spill disaster).
// NO W prefetch (r6: VGPR 100, occupancy down, slightly slower).
__device__ __forceinline__ void qkv_phase(
    const short* Xs, const bf16* __restrict__ Wall, const float* __restrict__ Ball,
    bf16* __restrict__ qo, bf16* __restrict__ kvo,
    int t, int n0, int N, int w, int l16, int lgrp) {
    size_t NB = (size_t)N * HD;
    int nsl = t ? 5 : 3;
    unsigned list = t ? 0x76431u : 0x520u;  // slice ids, 4 bits each
    for (int si = 0; si < nsl; ++si) {
        int g = (list >> (4 * si)) & 15;
        const bf16* WT = Wall + (size_t)g * 16384;
        bf16x8 Wc[2][4];
#pragma unroll
        for (int c2 = 0; c2 < 2; ++c2)
#pragma unroll
            for (int kk = 0; kk < 4; ++kk)
                Wc[c2][kk] = *(const bf16x8*)&WT[((w * 2 + c2) * 16 + l16) * 128 + kk * 32 + lgrp * 8];
        const float* bb = Ball + g * 128;
        f32x4 bv0 = *(const f32x4*)&bb[(w * 2 + 0) * 16 + lgrp * 4];
        f32x4 bv1 = *(const f32x4*)&bb[(w * 2 + 1) * 16 + lgrp * 4];
        f32x4 acc[8][2];
#pragma unroll
        for (int rt = 0; rt < 8; ++rt) { acc[rt][0] = bv0; acc[rt][1] = bv1; }
#pragma unroll
        for (int rt = 0; rt < 8; ++rt) {
#pragma unroll
            for (int kk = 0; kk < 4; ++kk) {
                bf16x8 xb = *(const bf16x8*)&Xs[(rt * 16 + l16) * 136 + kk * 32 + lgrp * 8];
                acc[rt][0] = __builtin_amdgcn_mfma_f32_16x16x32_bf16(Wc[0][kk], xb, acc[rt][0], 0, 0, 0);
                acc[rt][1] = __builtin_amdgcn_mfma_f32_16x16x32_bf16(Wc[1][kk], xb, acc[rt][1], 0, 0, 0);
            }
        }
        // epilogue: q -> [g][node][128]; K/V -> interleaved [r][node][K|V] 256-elem records
        unsigned short* outp;
        int rowStride, off2;
        if (g < 2) {
            outp = (unsigned short*)(qo + (size_t)g * NB);
            rowStride = HD; off2 = 0;
        } else {
            int gi = g - 2, r = gi % 3, isV = gi / 3;
            outp = (unsigned short*)(kvo + (size_t)r * N * 256);
            rowStride = 256; off2 = isV * 128;
        }
#pragma unroll
        for (int rt = 0; rt < 8; ++rt) {
            int node = n0 + rt * 16 + l16;
            if (node < N) {
#pragma unroll
                for (int c2 = 0; c2 < 2; ++c2) {
                    short4v s = pack4(acc[rt][c2][0], acc[rt][c2][1], acc[rt][c2][2], acc[rt][c2][3]);
                    *(short4v*)(outp + (size_t)node * rowStride + off2 + (w * 2 + c2) * 16 + lgrp * 4) = s;
                }
            }
        }
    }
}

// ---------------- fused: initial projection (bf16 state out) + layer-0 qkv ----------------
// t1 tiles launch first (5-slice blocks are longer; drain the tail on 3-slice t0 blocks)
__global__ __launch_bounds__(256) void proj_qkv(
    const float* __restrict__ xr, const float* __restrict__ xsi,
    const bf16* __restrict__ WrT, const float* __restrict__ br,
    const bf16* __restrict__ WsT, const float* __restrict__ bs,
    bf16* __restrict__ xsb,
    const bf16* __restrict__ Wall, const float* __restrict__ Ball,
    bf16* __restrict__ qo, bf16* __restrict__ kvo, int N, int nb0) {
    __shared__ short Xs[128 * 136];
    int b = blockIdx.x;
    int t = b < nb0 ? 1 : 0;
    int blk = t ? b : b - nb0;
    int tid = threadIdx.x;
    int w = tid >> 6, lane = tid & 63, l16 = lane & 15, lgrp = lane >> 4;
    int n0 = blk * 128;
    int rowbase = n0 + w * 32;
    int K = t ? 32 : 64;
    const float* X = t ? xsi : xr;
    const bf16* WT = t ? WsT : WrT;  // [128][K]
    const float* bb = t ? bs : br;
    f32x4 acc[2][8];
#pragma unroll
    for (int c = 0; c < 8; ++c) {
        f32x4 bv = *(const f32x4*)&bb[c * 16 + lgrp * 4];
        acc[0][c] = bv; acc[1][c] = bv;
    }
    int r0 = rowbase + l16, r1 = rowbase + 16 + l16;
    bool v0 = r0 < N, v1 = r1 < N;
    size_t b0 = (size_t)(v0 ? r0 : 0) * K, b1 = (size_t)(v1 ? r1 : 0) * K;
    int nkk = K >> 5;
    for (int kk = 0; kk < nkk; ++kk) {
        int ko = kk * 32 + lgrp * 8;
        f32x4 lo0 = {0,0,0,0}, hi0 = {0,0,0,0}, lo1 = {0,0,0,0}, hi1 = {0,0,0,0};
        if (v0) { lo0 = *(const f32x4*)&X[b0 + ko]; hi0 = *(const f32x4*)&X[b0 + ko + 4]; }
        if (v1) { lo1 = *(const f32x4*)&X[b1 + ko]; hi1 = *(const f32x4*)&X[b1 + ko + 4]; }
        bf16x8 x0 = pack8(lo0, hi0);
        bf16x8 x1 = pack8(lo1, hi1);
#pragma unroll
        for (int c = 0; c < 8; ++c) {
            bf16x8 wa = *(const bf16x8*)&WT[(size_t)(c * 16 + l16) * K + ko];
            acc[0][c] = __builtin_amdgcn_mfma_f32_16x16x32_bf16(wa, x0, acc[0][c], 0, 0, 0);
            acc[1][c] = __builtin_amdgcn_mfma_f32_16x16x32_bf16(wa, x1, acc[1][c], 0, 0, 0);
        }
    }
    // epilogue: write bf16 state + stage bf16 tile to LDS (row = tile-local node)
#pragma unroll
    for (int nt = 0; nt < 2; ++nt) {
        int lrow = w * 32 + nt * 16 + l16;
        int node = n0 + lrow;
        bool vn = node < N;
#pragma unroll
        for (int c = 0; c < 8; ++c) {
            int col = c * 16 + lgrp * 4;
            short4v s = pack4(acc[nt][c][0], acc[nt][c][1], acc[nt][c][2], acc[nt][c][3]);
            if (vn) *(short4v*)((unsigned short*)xsb + ((size_t)t * N + node) * HD + col) = s;
            *(short4v*)&Xs[lrow * 136 + col] = s;
        }
    }
    __syncthreads();
    qkv_phase(Xs, Wall, Ball, qo, kvo, t, n0, N, w, l16, lgrp);
}

// ------------- dst-centric gather: ONE WAVE64 PER NODE -------------
// Lane l reads record byte l*8: lanes 0-31 = K half, lanes 32-63 = V half -> the whole
// 512B record is ONE fully-contiguous load instruction (was 2 per 32-lane group).
// No degree divergence (old: two nodes per wave ran max(dgA,dgB) iterations, ~20% waste).
__global__ __launch_bounds__(256) void gather_kernel(
    const int* __restrict__ adj, const int* __restrict__ deg,
    const bf16* __restrict__ q, const bf16* __restrict__ kv,
    const float* __restrict__ prel, bf16* __restrict__ g, int N2, int N) {
    int grp = (blockIdx.x * 256 + threadIdx.x) >> 6;  // node in [0, 2N), one per wave
    int lane = threadIdx.x & 63;
    if (grp >= N2) return;
    int h = (lane & 31) >> 3;  // head of this lane's 4-elem chunk (K side and V side alike)

    ushort4 qa = *((const ushort4*)(q + (size_t)grp * HD) + (lane & 31));
    float q0 = bf2f(qa.x), q1 = bf2f(qa.y), q2 = bf2f(qa.z), q3 = bf2f(qa.w);
    const float is = 0.17677669529663687f; // 1/sqrt(32)
    float pr0 = prel[0 * H + h] * is, pr1 = prel[1 * H + h] * is, pr2 = prel[2 * H + h] * is;

    float m0 = 0.f, m1 = 0.f, m2 = 0.f, m3 = 0.f, dacc = 0.f;
    int dg = deg[grp]; if (dg > SLOTS) dg = SLOTS;
    const int* lst = adj + (size_t)grp * SLOTS;
    int mye = (lane < dg) ? lst[lane] : 0;  // one coalesced 256B read of the edge list

    if (dg > 0) {
        int ecur = __shfl(mye, 0);
        const bf16* base = kv + ((size_t)(ecur >> 20) * N + (ecur & 0xFFFFF)) * 256;
        ushort4 ra = *((const ushort4*)base + lane);  // whole record in one instruction
        for (int i = 0; i < dg; ++i) {
            int en = 0;
            ushort4 ran = {0, 0, 0, 0};
            if (i + 1 < dg) {  // prefetch next edge's record before processing current
                en = __shfl(mye, i + 1);
                const bf16* basen = kv + ((size_t)(en >> 20) * N + (en & 0xFFFFF)) * 256;
                ran = *((const ushort4*)basen + lane);
            }
            int r = ecur >> 20;
            // K-side partial dot (garbage on V lanes, fixed by the broadcast below)
            float p = q0 * bf2f(ra.x) + q1 * bf2f(ra.y) + q2 * bf2f(ra.z) + q3 * bf2f(ra.w);
            p += __shfl_xor(p, 1);
            p += __shfl_xor(p, 2);
            p += __shfl_xor(p, 4);
            p = __shfl(p, lane & 31);  // V lanes receive their head's K-side score
            float prv = (r == 0) ? pr0 : ((r == 1) ? pr1 : pr2);
            float eh = __expf(p * prv); // max-subtraction dropped: mathematically identical
            // V accumulation: meaningful on lanes 32-63 (ra there holds V elems (lane-32)*4..+3)
            m0 = fmaf(eh, bf2f(ra.x), m0);
            m1 = fmaf(eh, bf2f(ra.y), m1);
            m2 = fmaf(eh, bf2f(ra.z), m2);
            m3 = fmaf(eh, bf2f(ra.w), m3);
            dacc += eh;
            ecur = en; ra = ran;
        }
    }
    if (lane >= 32) {
        float inv = dacc > 0.f ? 1.f / dacc : 0.f;
        const float c = 0.70710678118654752f;
        float v0 = m0 * inv, v1 = m1 * inv, v2 = m2 * inv, v3 = m3 * inv;
        float g0 = 0.5f * v0 * (1.f + erff(v0 * c));
        float g1 = 0.5f * v1 * (1.f + erff(v1 * c));
        float g2 = 0.5f * v2 * (1.f + erff(v2 * c));
        float g3 = 0.5f * v3 * (1.f + erff(v3 * c));
        *((short4v*)(g + (size_t)grp * HD) + (lane - 32)) = pack4(g0, g1, g2, g3);
    }
}

// ------------- fused: out GEMM (layer l, bf16 state) + qkv (layer l+1); t1 first -------------
// Round-4 structure (verified best): 128-row tile, whole-tile acc[8][2], batched pv loads.
__global__ __launch_bounds__(256) void out_qkv(
    bf16* __restrict__ xsb, const bf16* __restrict__ gbuf,
    const bf16* __restrict__ WoT, const float* __restrict__ bo,
    const float* __restrict__ skip,
    const bf16* __restrict__ Wall, const float* __restrict__ Ball,
    bf16* __restrict__ qo, bf16* __restrict__ kvo, int N, int nb0) {
    __shared__ short S[128 * 136];
    int b = blockIdx.x;
    int t = b < nb0 ? 1 : 0;
    int blk = t ? b : b - nb0;
    int tid = threadIdx.x;
    int w = tid >> 6, lane = tid & 63, l16 = lane & 15, lgrp = lane >> 4;
    int n0 = blk * 128;
    size_t NB = (size_t)N * HD;
    const bf16* G = gbuf + (size_t)t * NB;
#pragma unroll
    for (int j = 0; j < 8; ++j) {
        int flat = tid + j * 256;
        int row = flat >> 4, c16 = flat & 15;
        bf16x8 v = {0, 0, 0, 0, 0, 0, 0, 0};
        if (n0 + row < N) v = *(const bf16x8*)&G[(size_t)(n0 + row) * HD + c16 * 8];
        *(bf16x8*)&S[row * 136 + c16 * 8] = v;
    }
    __syncthreads();
    const bf16* WT = WoT + (size_t)t * 16384;
    bf16x8 Wc[2][4];
#pragma unroll
    for (int c2 = 0; c2 < 2; ++c2)
#pragma unroll
        for (int kk = 0; kk < 4; ++kk)
            Wc[c2][kk] = *(const bf16x8*)&WT[((w * 2 + c2) * 16 + l16) * 128 + kk * 32 + lgrp * 8];
    const float* bb = bo + t * 128;
    f32x4 bv0 = *(const f32x4*)&bb[(w * 2 + 0) * 16 + lgrp * 4];
    f32x4 bv1 = *(const f32x4*)&bb[(w * 2 + 1) * 16 + lgrp * 4];
    f32x4 acc[8][2];
#pragma unroll
    for (int rt = 0; rt < 8; ++rt) { acc[rt][0] = bv0; acc[rt][1] = bv1; }
#pragma unroll
    for (int rt = 0; rt < 8; ++rt) {
#pragma unroll
        for (int kk = 0; kk < 4; ++kk) {
            bf16x8 xb = *(const bf16x8*)&S[(rt * 16 + l16) * 136 + kk * 32 + lgrp * 8];
            acc[rt][0] = __builtin_amdgcn_mfma_f32_16x16x32_bf16(Wc[0][kk], xb, acc[rt][0], 0, 0, 0);
            acc[rt][1] = __builtin_amdgcn_mfma_f32_16x16x32_bf16(Wc[1][kk], xb, acc[rt][1], 0, 0, 0);
        }
    }
    float a = 1.f / (1.f + expf(-skip[t]));
    // batch all 16 independent xsb loads (prev-state gather) before the barrier:
    // HBM latency overlaps the barrier wait instead of serializing the blend loop
    short4v pv[8][2];
#pragma unroll
    for (int rt = 0; rt < 8; ++rt) {
        int node = n0 + rt * 16 + l16;
        size_t base = ((size_t)t * N + (size_t)(node < N ? node : 0)) * HD;
#pragma unroll
        for (int c2 = 0; c2 < 2; ++c2)
            pv[rt][c2] = *(const short4v*)((const unsigned short*)xsb + base + (w * 2 + c2) * 16 + lgrp * 4);
    }
    __syncthreads();  // all reads of S done; safe to overwrite with the new tile
#pragma unroll
    for (int rt = 0; rt < 8; ++rt) {
        int lrow = rt * 16 + l16;
        int node = n0 + lrow;
        bool vn = node < N;
#pragma unroll
        for (int c2 = 0; c2 < 2; ++c2) {
            int col = (w * 2 + c2) * 16 + lgrp * 4;
            short4v s;
            if (vn) {
                size_t idx = ((size_t)t * N + node) * HD + col;
                f32x4 o;
#pragma unroll
                for (int j = 0; j < 4; ++j)
                    o[j] = fmaxf(a * acc[rt][c2][j] + (1.f - a) * bf2f((unsigned short)pv[rt][c2][j]), 0.f);
                s = pack4(o[0], o[1], o[2], o[3]);
                *(short4v*)((unsigned short*)xsb + idx) = s;
            } else {
                s = (short4v){0, 0, 0, 0};
            }
            *(short4v*)&S[lrow * 136 + col] = s;
        }
    }
    __syncthreads();
    qkv_phase(S, Wall, Ball, qo, kvo, t, n0, N, w, l16, lgrp);
}

// ------------- final output: G tile in LDS; skip blend vs bf16 prev, ReLU, fp32 d_out -------------
__global__ __launch_bounds__(256) void out_gemm(
    float* __restrict__ xs, const bf16* __restrict__ xsb, const bf16* __restrict__ gbuf,
    const bf16* __restrict__ WoT, const float* __restrict__ bo,
    const float* __restrict__ skip, int N, int nb0) {
    __shared__ short Gs[128 * 136];
    int b = blockIdx.x;
    int t = b >= nb0 ? 1 : 0;
    int blk = t ? b - nb0 : b;
    int tid = threadIdx.x;
    int w = tid >> 6, lane = tid & 63, l16 = lane & 15, lgrp = lane >> 4;
    int n0 = blk * 128;
    size_t NB = (size_t)N * HD;
    const bf16* G = gbuf + (size_t)t * NB;
#pragma unroll
    for (int j = 0; j < 8; ++j) {
        int flat = tid + j * 256;
        int row = flat >> 4, c16 = flat & 15;
        bf16x8 v = {0, 0, 0, 0, 0, 0, 0, 0};
        if (n0 + row < N) v = *(const bf16x8*)&G[(size_t)(n0 + row) * HD + c16 * 8];
        *(bf16x8*)&Gs[row * 136 + c16 * 8] = v;
    }
    __syncthreads();
    const bf16* WT = WoT + (size_t)t * 16384;
    bf16x8 Wc[2][4];
#pragma unroll
    for (int c2 = 0; c2 < 2; ++c2)
#pragma unroll
        for (int kk = 0; kk < 4; ++kk)
            Wc[c2][kk] = *(const bf16x8*)&WT[((w * 2 + c2) * 16 + l16) * 128 + kk * 32 + lgrp * 8];
    const float* bb = bo + t * 128;
    f32x4 bv0 = *(const f32x4*)&bb[(w * 2 + 0) * 16 + lgrp * 4];
    f32x4 bv1 = *(const f32x4*)&bb[(w * 2 + 1) * 16 + lgrp * 4];
    f32x4 acc[8][2];
#pragma unroll
    for (int rt = 0; rt < 8; ++rt) { acc[rt][0] = bv0; acc[rt][1] = bv1; }
#pragma unroll
    for (int rt = 0; rt < 8; ++rt) {
#pragma unroll
        for (int kk = 0; kk < 4; ++kk) {
            bf16x8 xb = *(const bf16x8*)&Gs[(rt * 16 + l16) * 136 + kk * 32 + lgrp * 8];
            acc[rt][0] = __builtin_amdgcn_mfma_f32_16x16x32_bf16(Wc[0][kk], xb, acc[rt][0], 0, 0, 0);
            acc[rt][1] = __builtin_amdgcn_mfma_f32_16x16x32_bf16(Wc[1][kk], xb, acc[rt][1], 0, 0, 0);
        }
    }
    float a = 1.f / (1.f + expf(-skip[t]));
    // batch the 16 independent xsb loads, then blend/store
    short4v pv[8][2];
#pragma unroll
    for (int rt = 0; rt < 8; ++rt) {
        int node = n0 + rt * 16 + l16;
        size_t base = ((size_t)t * N + (size_t)(node < N ? node : 0)) * HD;
#pragma unroll
        for (int c2 = 0; c2 < 2; ++c2)
            pv[rt][c2] = *(const short4v*)((const unsigned short*)xsb + base + (w * 2 + c2) * 16 + lgrp * 4);
    }
#pragma unroll
    for (int rt = 0; rt < 8; ++rt) {
        int node = n0 + rt * 16 + l16;
        if (node < N) {
#pragma unroll
            for (int c2 = 0; c2 < 2; ++c2) {
                size_t idx = ((size_t)t * N + node) * HD + (w * 2 + c2) * 16 + lgrp * 4;
                f32x4 o;
#pragma unroll
                for (int j = 0; j < 4; ++j)
                    o[j] = fmaxf(a * acc[rt][c2][j] + (1.f - a) * bf2f((unsigned short)pv[rt][c2][j]), 0.f);
                *(f32x4*)&xs[idx] = o;
            }
        }
    }
}

extern "C" void kernel_launch(void* const* d_in, const int* in_sizes, int n_in,
                              void* d_out, int out_size, void* d_ws, size_t ws_size,
                              hipStream_t stream) {
    const float* x_region = (const float*)d_in[0];
    const float* x_site   = (const float*)d_in[1];
    const float* pWr  = (const float*)d_in[2];
    const float* pbr  = (const float*)d_in[3];
    const float* pWs  = (const float*)d_in[4];
    const float* pbs  = (const float*)d_in[5];
    const float* Wk   = (const float*)d_in[6];
    const float* bk   = (const float*)d_in[7];
    const float* Wq   = (const float*)d_in[8];
    const float* bq   = (const float*)d_in[9];
    const float* Wv   = (const float*)d_in[10];
    const float* bv   = (const float*)d_in[11];
    const float* Wo   = (const float*)d_in[12];
    const float* bo   = (const float*)d_in[13];
    const float* skip = (const float*)d_in[14];
    const float* Krel = (const float*)d_in[15];
    const float* Vrel = (const float*)d_in[16];
    const float* prel = (const float*)d_in[17];
    const int* e0 = (const int*)d_in[18];
    const int* e1 = (const int*)d_in[19];
    const int* e2 = (const int*)d_in[20];

    int N = in_sizes[0] / 64;   // 100000
    int E = in_sizes[18] / 2;   // 200000
    int nb0 = (N + 127) / 128;
    int N2 = 2 * N;

    float* xs = (float*)d_out;  // [2][N][128] fp32 — written once by the final out_gemm

    size_t NB = (size_t)N * HD;
    char* p = (char*)d_ws;
    bf16* q_bf  = (bf16*)p; p += 2 * NB * sizeof(bf16);          // [2][N][128]
    bf16* kv_bf = (bf16*)p; p += 3 * (size_t)N * 256 * sizeof(bf16); // [3][N][K(128)|V(128)]
    bf16* g_bf  = (bf16*)p; p += 2 * NB * sizeof(bf16);
    bf16* xsb   = (bf16*)p; p += 2 * NB * sizeof(bf16);          // bf16 node state (intermediate xs)
    int*  adj   = (int*)p;  p += (size_t)N2 * SLOTS * sizeof(int);
    int*  deg   = (int*)p;  p += (size_t)N2 * sizeof(int);
    bf16* PWrT  = (bf16*)p; p += 8192 * sizeof(bf16);            // [128][64]
    bf16* PWsT  = (bf16*)p; p += 4096 * sizeof(bf16);            // [128][32]
    bf16* Wall  = (bf16*)p; p += 2 * 8 * 16384 * sizeof(bf16);   // [L][8][128][128]
    bf16* WoT_a = (bf16*)p; p += 2 * 2 * 16384 * sizeof(bf16);   // [L][2][128][128]
    float* Ball = (float*)p; p += 2 * 8 * 128 * sizeof(float);   // [L][8][128]
    (void)ws_size; (void)n_in; (void)out_size;

    // ---- adjacency (edge lists are launch-constant) ----
    hipMemsetAsync(deg, 0, (size_t)N2 * sizeof(int), stream);
    int bgrid = (E + 255) / 256;
    build_adj<<<bgrid, 256, 0, stream>>>(e0, adj, deg, N, 0, E); // r2s -> dst type 1
    build_adj<<<bgrid, 256, 0, stream>>>(e1, adj, deg, 0, 1, E); // s2r -> dst type 0
    build_adj<<<bgrid, 256, 0, stream>>>(e2, adj, deg, N, 2, E); // s2s -> dst type 1

    // ---- weight prep ----
    transpose_bf16<<<32, 256, 0, stream>>>(pWr, PWrT, 64, 128, 64, 8192);
    transpose_bf16<<<16, 256, 0, stream>>>(pWs, PWsT, 32, 128, 32, 4096);
    for (int l = 0; l < 2; ++l) {
        transpose_bf16<<<128, 256, 0, stream>>>(Wq + (size_t)l * 2 * 16384,
                                                Wall + (size_t)l * 8 * 16384, 128, 128, 128, 32768);
        transpose_bf16<<<128, 256, 0, stream>>>(Wo + (size_t)l * 2 * 16384,
                                                WoT_a + (size_t)l * 2 * 16384, 128, 128, 128, 32768);
    }
    fuse_relw<<<768, 256, 0, stream>>>(Wk, Wv, Krel, Vrel, Wall);
    fuse_relb<<<8, 256, 0, stream>>>(bk, bv, bq, Krel, Vrel, Ball);

    int ggrid = ((size_t)N2 * 64 + 255) / 256;

    // layer 0: fused proj + qkv (bf16 node state)
    proj_qkv<<<2 * nb0, 256, 0, stream>>>(
        x_region, x_site, PWrT, pbr, PWsT, pbs, xsb,
        Wall, Ball, q_bf, kv_bf, N, nb0);
    gather_kernel<<<ggrid, 256, 0, stream>>>(
        adj, deg, q_bf, kv_bf, prel, g_bf, N2, N);
    // layer seam: fused out(l0) + qkv(l1), bf16 state round-trip only
    out_qkv<<<2 * nb0, 256, 0, stream>>>(
        xsb, g_bf, WoT_a, bo, skip,
        Wall + (size_t)8 * 16384, Ball + 8 * 128, q_bf, kv_bf, N, nb0);
    gather_kernel<<<ggrid, 256, 0, stream>>>(
        adj, deg, q_bf, kv_bf, prel + 12, g_bf, N2, N);
    // final out (l1): blend vs bf16 prev, write fp32 d_out
    out_gemm<<<2 * nb0, 256, 0, stream>>>(
        xs, xsb, g_bf, WoT_a + (size_t)2 * 16384, bo + 2 * HD, skip + 2, N, nb0);
}

// Round 8
// 537.734 us; speedup vs baseline: 1.1311x; 1.1311x over previous
//
#include <hip/hip_runtime.h>
#include <hip/hip_bf16.h>

#define HD 128
#define H 4
#define D 32
#define SLOTS 64

typedef __hip_bfloat16 bf16;
typedef __attribute__((ext_vector_type(8))) short bf16x8;
typedef __attribute__((ext_vector_type(4))) float f32x4;
typedef __attribute__((ext_vector_type(4))) short short4v;

__device__ __forceinline__ float bf2f(unsigned short u) {
    union { unsigned int i; float f; } v; v.i = ((unsigned int)u) << 16; return v.f;
}
__device__ __forceinline__ short f2bf(float f) {
    union { float f; unsigned u; } v; v.f = f;
    unsigned r = v.u + 0x7fff + ((v.u >> 16) & 1);
    return (short)(r >> 16);
}
// HW packed fp32->bf16 (RNE), 2 values/instr
__device__ __forceinline__ short4v pack4(float a0, float a1, float a2, float a3) {
    union { unsigned u[2]; short4v v; } r;
    asm("v_cvt_pk_bf16_f32 %0, %1, %2" : "=v"(r.u[0]) : "v"(a0), "v"(a1));
    asm("v_cvt_pk_bf16_f32 %0, %1, %2" : "=v"(r.u[1]) : "v"(a2), "v"(a3));
    return r.v;
}
__device__ __forceinline__ bf16x8 pack8(const f32x4 lo, const f32x4 hi) {
    union { unsigned u[4]; bf16x8 v; } r;
    asm("v_cvt_pk_bf16_f32 %0, %1, %2" : "=v"(r.u[0]) : "v"(lo[0]), "v"(lo[1]));
    asm("v_cvt_pk_bf16_f32 %0, %1, %2" : "=v"(r.u[1]) : "v"(lo[2]), "v"(lo[3]));
    asm("v_cvt_pk_bf16_f32 %0, %1, %2" : "=v"(r.u[2]) : "v"(hi[0]), "v"(hi[1]));
    asm("v_cvt_pk_bf16_f32 %0, %1, %2" : "=v"(r.u[3]) : "v"(hi[2]), "v"(hi[3]));
    return r.v;
}
// 8-lane-group sum at VALU speed via DPP (quad_perm xor1, xor2, row_half_mirror).
// Replaces 3 serial ds_swizzle shfl_xor (~120cy chain) with ~15cy of VALU.
// Groups are 8-lane aligned; DPP patterns never read outside the 8-lane group.
__device__ __forceinline__ float dpp8_sum(float p) {
    union { int i; float f; } u, v;
    u.f = p;
    v.i = __builtin_amdgcn_mov_dpp(u.i, 0xB1, 0xF, 0xF, true);  p += v.f; u.f = p;  // quad_perm [1,0,3,2] = xor1
    v.i = __builtin_amdgcn_mov_dpp(u.i, 0x4E, 0xF, 0xF, true);  p += v.f; u.f = p;  // quad_perm [2,3,0,1] = xor2
    v.i = __builtin_amdgcn_mov_dpp(u.i, 0x141, 0xF, 0xF, true); p += v.f;           // row_half_mirror (cross-quad within 8)
    return p;
}

// ---------------- weight pre-transpose: dst[b][c][kd] = bf16(src[b][k][c]) ----------------
__global__ __launch_bounds__(256) void transpose_bf16(
    const float* __restrict__ src, bf16* __restrict__ dst, int K, int C, int Kd, int total) {
    int i = blockIdx.x * 256 + threadIdx.x;
    if (i >= total) return;
    int kd = i % Kd; int rem = i / Kd; int c = rem % C; int b = rem / C;
    float v = (kd < K) ? src[((size_t)b * K + kd) * C + c] : 0.f;
    ((unsigned short*)dst)[i] = (unsigned short)f2bf(v);
}

// ---------------- fuse relation transforms into k/v weights ----------------
// Wall layout per layer: slot 0,1 = WqT(t0,t1); 2..4 = fused K rel0..2; 5..7 = fused V rel0..2
__global__ __launch_bounds__(256) void fuse_relw(
    const float* __restrict__ Wk, const float* __restrict__ Wv,
    const float* __restrict__ Krel, const float* __restrict__ Vrel,
    bf16* __restrict__ Wall) {
    int gid = blockIdx.x * 256 + threadIdx.x;  // 12 * 16384
    int m = gid >> 14;
    int idx = gid & 16383;
    int ep = idx >> 7, i = idx & 127;
    int l = m / 6, kv = (m / 3) & 1, r = m % 3;
    int s = (r == 0) ? 0 : 1;
    const float* W = (kv ? Wv : Wk) + ((size_t)(l * 2 + s)) * 16384;
    const float* R = (kv ? Vrel : Krel) + ((size_t)(l * 3 + r)) * 4096;
    int h = ep >> 5, e = ep & 31;
    float acc = 0.f;
#pragma unroll
    for (int d = 0; d < 32; ++d)
        acc = fmaf(W[i * 128 + h * 32 + d], R[h * 1024 + d * 32 + e], acc);
    int slot = l * 8 + 2 + kv * 3 + r;
    ((unsigned short*)Wall)[(size_t)slot * 16384 + ep * 128 + i] = (unsigned short)f2bf(acc);
}

// Ball layout per layer: [8][128] fp32; slots 0,1 = bq; 2..4 fused bk; 5..7 fused bv
__global__ __launch_bounds__(256) void fuse_relb(
    const float* __restrict__ bk, const float* __restrict__ bv, const float* __restrict__ bq,
    const float* __restrict__ Krel, const float* __restrict__ Vrel,
    float* __restrict__ Ball) {
    int gid = blockIdx.x * 256 + threadIdx.x;  // 2048
    if (gid >= 2048) return;
    int col = gid & 127, m = gid >> 7;
    int l = m >> 3, g = m & 7;
    float val;
    if (g < 2) {
        val = bq[(l * 2 + g) * 128 + col];
    } else {
        int kv = (g - 2) / 3, r = (g - 2) % 3, s = (r == 0) ? 0 : 1;
        const float* b = (kv ? bv : bk) + (size_t)(l * 2 + s) * 128;
        const float* R = (kv ? Vrel : Krel) + (size_t)(l * 3 + r) * 4096;
        int h = col >> 5, e = col & 31;
        float acc = 0.f;
#pragma unroll
        for (int d = 0; d < 32; ++d)
            acc = fmaf(b[h * 32 + d], R[h * 1024 + d * 32 + e], acc);
        val = acc;
    }
    Ball[gid] = val;
}

// ---------------- adjacency build: fixed 64 slots per dst node ----------------
__global__ __launch_bounds__(256) void build_adj(
    const int* __restrict__ edge, int* __restrict__ adj, int* __restrict__ deg,
    int dstBase, int rel, int E) {
    int i = blockIdx.x * 256 + threadIdx.x;
    if (i >= E) return;
    int src = edge[i];
    int dst = edge[E + i];
    int slot = atomicAdd(deg + dstBase + dst, 1);
    if (slot < SLOTS) adj[(size_t)(dstBase + dst) * SLOTS + slot] = src | (rel << 20);
}

// ---------------- MFMA 16x16x32, A=weightT (outcol rows), B=X^T (node cols) ----------------
// A-frag: lane holds A[row=l&15][k=(l>>4)*8+j]  -> row indexes OUTPUT COLUMN
// B-frag: lane holds B[k=(l>>4)*8+j][col=l&15]  -> col indexes NODE; element = X[node][k]
// D:      lane reg j = D[outcol=(l>>4)*4+j (+tile)][node=l&15]

// ---------------- shared qkv slice phase: reads X tile from LDS ----------------
// type 0 -> slices {0,2,5}; type 1 -> {1,3,4,6,7}. Wave w owns outcols [w*32, w*32+32).
// OUTPUT: q slices (g<2) -> q[g][node][128]; K/V slices -> kv[r][node][512B record: K|V]
// Round-4 structure (verified best). NO launch-bounds clamp (r1/r2: 64-VGPR spill disaster).
// NO W prefetch (r6: VGPR 100, occupancy down, slightly slower).
__device__ __forceinline__ void qkv_phase(
    const short* Xs, const bf16* __restrict__ Wall, const float* __restrict__ Ball,
    bf16* __restrict__ qo, bf16* __restrict__ kvo,
    int t, int n0, int N, int w, int l16, int lgrp) {
    size_t NB = (size_t)N * HD;
    int nsl = t ? 5 : 3;
    unsigned list = t ? 0x76431u : 0x520u;  // slice ids, 4 bits each
    for (int si = 0; si < nsl; ++si) {
        int g = (list >> (4 * si)) & 15;
        const bf16* WT = Wall + (size_t)g * 16384;
        bf16x8 Wc[2][4];
#pragma unroll
        for (int c2 = 0; c2 < 2; ++c2)
#pragma unroll
            for (int kk = 0; kk < 4; ++kk)
                Wc[c2][kk] = *(const bf16x8*)&WT[((w * 2 + c2) * 16 + l16) * 128 + kk * 32 + lgrp * 8];
        const float* bb = Ball + g * 128;
        f32x4 bv0 = *(const f32x4*)&bb[(w * 2 + 0) * 16 + lgrp * 4];
        f32x4 bv1 = *(const f32x4*)&bb[(w * 2 + 1) * 16 + lgrp * 4];
        f32x4 acc[8][2];
#pragma unroll
        for (int rt = 0; rt < 8; ++rt) { acc[rt][0] = bv0; acc[rt][1] = bv1; }
#pragma unroll
        for (int rt = 0; rt < 8; ++rt) {
#pragma unroll
            for (int kk = 0; kk < 4; ++kk) {
                bf16x8 xb = *(const bf16x8*)&Xs[(rt * 16 + l16) * 136 + kk * 32 + lgrp * 8];
                acc[rt][0] = __builtin_amdgcn_mfma_f32_16x16x32_bf16(Wc[0][kk], xb, acc[rt][0], 0, 0, 0);
                acc[rt][1] = __builtin_amdgcn_mfma_f32_16x16x32_bf16(Wc[1][kk], xb, acc[rt][1], 0, 0, 0);
            }
        }
        // epilogue: q -> [g][node][128]; K/V -> interleaved [r][node][K|V] 256-elem records
        unsigned short* outp;
        int rowStride, off2;
        if (g < 2) {
            outp = (unsigned short*)(qo + (size_t)g * NB);
            rowStride = HD; off2 = 0;
        } else {
            int gi = g - 2, r = gi % 3, isV = gi / 3;
            outp = (unsigned short*)(kvo + (size_t)r * N * 256);
            rowStride = 256; off2 = isV * 128;
        }
#pragma unroll
        for (int rt = 0; rt < 8; ++rt) {
            int node = n0 + rt * 16 + l16;
            if (node < N) {
#pragma unroll
                for (int c2 = 0; c2 < 2; ++c2) {
                    short4v s = pack4(acc[rt][c2][0], acc[rt][c2][1], acc[rt][c2][2], acc[rt][c2][3]);
                    *(short4v*)(outp + (size_t)node * rowStride + off2 + (w * 2 + c2) * 16 + lgrp * 4) = s;
                }
            }
        }
    }
}

// ---------------- fused: initial projection (bf16 state out) + layer-0 qkv ----------------
// t1 tiles launch first (5-slice blocks are longer; drain the tail on 3-slice t0 blocks)
__global__ __launch_bounds__(256) void proj_qkv(
    const float* __restrict__ xr, const float* __restrict__ xsi,
    const bf16* __restrict__ WrT, const float* __restrict__ br,
    const bf16* __restrict__ WsT, const float* __restrict__ bs,
    bf16* __restrict__ xsb,
    const bf16* __restrict__ Wall, const float* __restrict__ Ball,
    bf16* __restrict__ qo, bf16* __restrict__ kvo, int N, int nb0) {
    __shared__ short Xs[128 * 136];
    int b = blockIdx.x;
    int t = b < nb0 ? 1 : 0;
    int blk = t ? b : b - nb0;
    int tid = threadIdx.x;
    int w = tid >> 6, lane = tid & 63, l16 = lane & 15, lgrp = lane >> 4;
    int n0 = blk * 128;
    int rowbase = n0 + w * 32;
    int K = t ? 32 : 64;
    const float* X = t ? xsi : xr;
    const bf16* WT = t ? WsT : WrT;  // [128][K]
    const float* bb = t ? bs : br;
    f32x4 acc[2][8];
#pragma unroll
    for (int c = 0; c < 8; ++c) {
        f32x4 bv = *(const f32x4*)&bb[c * 16 + lgrp * 4];
        acc[0][c] = bv; acc[1][c] = bv;
    }
    int r0 = rowbase + l16, r1 = rowbase + 16 + l16;
    bool v0 = r0 < N, v1 = r1 < N;
    size_t b0 = (size_t)(v0 ? r0 : 0) * K, b1 = (size_t)(v1 ? r1 : 0) * K;
    int nkk = K >> 5;
    for (int kk = 0; kk < nkk; ++kk) {
        int ko = kk * 32 + lgrp * 8;
        f32x4 lo0 = {0,0,0,0}, hi0 = {0,0,0,0}, lo1 = {0,0,0,0}, hi1 = {0,0,0,0};
        if (v0) { lo0 = *(const f32x4*)&X[b0 + ko]; hi0 = *(const f32x4*)&X[b0 + ko + 4]; }
        if (v1) { lo1 = *(const f32x4*)&X[b1 + ko]; hi1 = *(const f32x4*)&X[b1 + ko + 4]; }
        bf16x8 x0 = pack8(lo0, hi0);
        bf16x8 x1 = pack8(lo1, hi1);
#pragma unroll
        for (int c = 0; c < 8; ++c) {
            bf16x8 wa = *(const bf16x8*)&WT[(size_t)(c * 16 + l16) * K + ko];
            acc[0][c] = __builtin_amdgcn_mfma_f32_16x16x32_bf16(wa, x0, acc[0][c], 0, 0, 0);
            acc[1][c] = __builtin_amdgcn_mfma_f32_16x16x32_bf16(wa, x1, acc[1][c], 0, 0, 0);
        }
    }
    // epilogue: write bf16 state + stage bf16 tile to LDS (row = tile-local node)
#pragma unroll
    for (int nt = 0; nt < 2; ++nt) {
        int lrow = w * 32 + nt * 16 + l16;
        int node = n0 + lrow;
        bool vn = node < N;
#pragma unroll
        for (int c = 0; c < 8; ++c) {
            int col = c * 16 + lgrp * 4;
            short4v s = pack4(acc[nt][c][0], acc[nt][c][1], acc[nt][c][2], acc[nt][c][3]);
            if (vn) *(short4v*)((unsigned short*)xsb + ((size_t)t * N + node) * HD + col) = s;
            *(short4v*)&Xs[lrow * 136 + col] = s;
        }
    }
    __syncthreads();
    qkv_phase(Xs, Wall, Ball, qo, kvo, t, n0, N, w, l16, lgrp);
}

// ------------- dst-centric gather: interleaved K|V records, width-32 shfl, 2-deep pipeline -------------
// r4 structure (two nodes per wave — iteration cost amortized across both; r7's one-wave-per-node
// variant ran ~1.6x more loop executions and regressed). Score reduce now DPP (VALU) not ds_swizzle.
__global__ __launch_bounds__(256) void gather_kernel(
    const int* __restrict__ adj, const int* __restrict__ deg,
    const bf16* __restrict__ q, const bf16* __restrict__ kv,
    const float* __restrict__ prel, bf16* __restrict__ g, int N2, int N) {
    int grp = (blockIdx.x * 256 + threadIdx.x) >> 5;  // node in [0, 2N)
    int lane = threadIdx.x & 31;
    if (grp >= N2) return;
    int h = lane >> 3;

    ushort4 qa = *((const ushort4*)(q + (size_t)grp * HD) + lane);
    float q0 = bf2f(qa.x), q1 = bf2f(qa.y), q2 = bf2f(qa.z), q3 = bf2f(qa.w);
    const float is = 0.17677669529663687f; // 1/sqrt(32)
    float pr0 = prel[0 * H + h] * is, pr1 = prel[1 * H + h] * is, pr2 = prel[2 * H + h] * is;

    float m0 = 0.f, m1 = 0.f, m2 = 0.f, m3 = 0.f, dacc = 0.f;
    int dg = deg[grp]; if (dg > SLOTS) dg = SLOTS;
    const int* lst = adj + (size_t)grp * SLOTS;
    // one coalesced read of the edge list into lanes; broadcast via WIDTH-32 shfl
    // (wave=64 on CDNA: two 32-lane node groups share a wave)
    int myeA = (lane < dg) ? lst[lane] : 0;
    int myeB = (lane + 32 < dg) ? lst[lane + 32] : 0;

    if (dg > 0) {
        int ecur = __shfl(myeA, 0, 32);
        const bf16* base = kv + ((size_t)(ecur >> 20) * N + (ecur & 0xFFFFF)) * 256;
        ushort4 ka = *((const ushort4*)base + lane);
        ushort4 va = *((const ushort4*)base + 32 + lane);
        for (int i = 0; i < dg; ++i) {
            int en = 0;
            ushort4 kan = {0, 0, 0, 0}, van = {0, 0, 0, 0};
            if (i + 1 < dg) {  // prefetch next edge's record before processing current
                en = (i + 1 < 32) ? __shfl(myeA, i + 1, 32) : __shfl(myeB, i + 1 - 32, 32);
                const bf16* basen = kv + ((size_t)(en >> 20) * N + (en & 0xFFFFF)) * 256;
                kan = *((const ushort4*)basen + lane);
                van = *((const ushort4*)basen + 32 + lane);
            }
            int r = ecur >> 20;
            float p = q0 * bf2f(ka.x) + q1 * bf2f(ka.y) + q2 * bf2f(ka.z) + q3 * bf2f(ka.w);
            p = dpp8_sum(p);  // 8-lane head reduce at VALU speed (was 3 serial ds_swizzle)
            float prv = (r == 0) ? pr0 : ((r == 1) ? pr1 : pr2);
            float eh = __expf(p * prv); // max-subtraction dropped: mathematically identical
            m0 = fmaf(eh, bf2f(va.x), m0);
            m1 = fmaf(eh, bf2f(va.y), m1);
            m2 = fmaf(eh, bf2f(va.z), m2);
            m3 = fmaf(eh, bf2f(va.w), m3);
            dacc += eh;
            ecur = en; ka = kan; va = van;
        }
    }
    float inv = dacc > 0.f ? 1.f / dacc : 0.f;
    const float c = 0.70710678118654752f;
    float v0 = m0 * inv, v1 = m1 * inv, v2 = m2 * inv, v3 = m3 * inv;
    float g0 = 0.5f * v0 * (1.f + erff(v0 * c));
    float g1 = 0.5f * v1 * (1.f + erff(v1 * c));
    float g2 = 0.5f * v2 * (1.f + erff(v2 * c));
    float g3 = 0.5f * v3 * (1.f + erff(v3 * c));
    *((short4v*)(g + (size_t)grp * HD) + lane) = pack4(g0, g1, g2, g3);
}

// ------------- fused: out GEMM (layer l, bf16 state) + qkv (layer l+1); t1 first -------------
// Round-4 structure (verified best): 128-row tile, whole-tile acc[8][2], batched pv loads.
__global__ __launch_bounds__(256) void out_qkv(
    bf16* __restrict__ xsb, const bf16* __restrict__ gbuf,
    const bf16* __restrict__ WoT, const float* __restrict__ bo,
    const float* __restrict__ skip,
    const bf16* __restrict__ Wall, const float* __restrict__ Ball,
    bf16* __restrict__ qo, bf16* __restrict__ kvo, int N, int nb0) {
    __shared__ short S[128 * 136];
    int b = blockIdx.x;
    int t = b < nb0 ? 1 : 0;
    int blk = t ? b : b - nb0;
    int tid = threadIdx.x;
    int w = tid >> 6, lane = tid & 63, l16 = lane & 15, lgrp = lane >> 4;
    int n0 = blk * 128;
    size_t NB = (size_t)N * HD;
    const bf16* G = gbuf + (size_t)t * NB;
#pragma unroll
    for (int j = 0; j < 8; ++j) {
        int flat = tid + j * 256;
        int row = flat >> 4, c16 = flat & 15;
        bf16x8 v = {0, 0, 0, 0, 0, 0, 0, 0};
        if (n0 + row < N) v = *(const bf16x8*)&G[(size_t)(n0 + row) * HD + c16 * 8];
        *(bf16x8*)&S[row * 136 + c16 * 8] = v;
    }
    __syncthreads();
    const bf16* WT = WoT + (size_t)t * 16384;
    bf16x8 Wc[2][4];
#pragma unroll
    for (int c2 = 0; c2 < 2; ++c2)
#pragma unroll
        for (int kk = 0; kk < 4; ++kk)
            Wc[c2][kk] = *(const bf16x8*)&WT[((w * 2 + c2) * 16 + l16) * 128 + kk * 32 + lgrp * 8];
    const float* bb = bo + t * 128;
    f32x4 bv0 = *(const f32x4*)&bb[(w * 2 + 0) * 16 + lgrp * 4];
    f32x4 bv1 = *(const f32x4*)&bb[(w * 2 + 1) * 16 + lgrp * 4];
    f32x4 acc[8][2];
#pragma unroll
    for (int rt = 0; rt < 8; ++rt) { acc[rt][0] = bv0; acc[rt][1] = bv1; }
#pragma unroll
    for (int rt = 0; rt < 8; ++rt) {
#pragma unroll
        for (int kk = 0; kk < 4; ++kk) {
            bf16x8 xb = *(const bf16x8*)&S[(rt * 16 + l16) * 136 + kk * 32 + lgrp * 8];
            acc[rt][0] = __builtin_amdgcn_mfma_f32_16x16x32_bf16(Wc[0][kk], xb, acc[rt][0], 0, 0, 0);
            acc[rt][1] = __builtin_amdgcn_mfma_f32_16x16x32_bf16(Wc[1][kk], xb, acc[rt][1], 0, 0, 0);
        }
    }
    float a = 1.f / (1.f + expf(-skip[t]));
    // batch all 16 independent xsb loads (prev-state gather) before the barrier:
    // HBM latency overlaps the barrier wait instead of serializing the blend loop
    short4v pv[8][2];
#pragma unroll
    for (int rt = 0; rt < 8; ++rt) {
        int node = n0 + rt * 16 + l16;
        size_t base = ((size_t)t * N + (size_t)(node < N ? node : 0)) * HD;
#pragma unroll
        for (int c2 = 0; c2 < 2; ++c2)
            pv[rt][c2] = *(const short4v*)((const unsigned short*)xsb + base + (w * 2 + c2) * 16 + lgrp * 4);
    }
    __syncthreads();  // all reads of S done; safe to overwrite with the new tile
#pragma unroll
    for (int rt = 0; rt < 8; ++rt) {
        int lrow = rt * 16 + l16;
        int node = n0 + lrow;
        bool vn = node < N;
#pragma unroll
        for (int c2 = 0; c2 < 2; ++c2) {
            int col = (w * 2 + c2) * 16 + lgrp * 4;
            short4v s;
            if (vn) {
                size_t idx = ((size_t)t * N + node) * HD + col;
                f32x4 o;
#pragma unroll
                for (int j = 0; j < 4; ++j)
                    o[j] = fmaxf(a * acc[rt][c2][j] + (1.f - a) * bf2f((unsigned short)pv[rt][c2][j]), 0.f);
                s = pack4(o[0], o[1], o[2], o[3]);
                *(short4v*)((unsigned short*)xsb + idx) = s;
            } else {
                s = (short4v){0, 0, 0, 0};
            }
            *(short4v*)&S[lrow * 136 + col] = s;
        }
    }
    __syncthreads();
    qkv_phase(S, Wall, Ball, qo, kvo, t, n0, N, w, l16, lgrp);
}

// ------------- final output: G tile in LDS; skip blend vs bf16 prev, ReLU, fp32 d_out -------------
__global__ __launch_bounds__(256) void out_gemm(
    float* __restrict__ xs, const bf16* __restrict__ xsb, const bf16* __restrict__ gbuf,
    const bf16* __restrict__ WoT, const float* __restrict__ bo,
    const float* __restrict__ skip, int N, int nb0) {
    __shared__ short Gs[128 * 136];
    int b = blockIdx.x;
    int t = b >= nb0 ? 1 : 0;
    int blk = t ? b - nb0 : b;
    int tid = threadIdx.x;
    int w = tid >> 6, lane = tid & 63, l16 = lane & 15, lgrp = lane >> 4;
    int n0 = blk * 128;
    size_t NB = (size_t)N * HD;
    const bf16* G = gbuf + (size_t)t * NB;
#pragma unroll
    for (int j = 0; j < 8; ++j) {
        int flat = tid + j * 256;
        int row = flat >> 4, c16 = flat & 15;
        bf16x8 v = {0, 0, 0, 0, 0, 0, 0, 0};
        if (n0 + row < N) v = *(const bf16x8*)&G[(size_t)(n0 + row) * HD + c16 * 8];
        *(bf16x8*)&Gs[row * 136 + c16 * 8] = v;
    }
    __syncthreads();
    const bf16* WT = WoT + (size_t)t * 16384;
    bf16x8 Wc[2][4];
#pragma unroll
    for (int c2 = 0; c2 < 2; ++c2)
#pragma unroll
        for (int kk = 0; kk < 4; ++kk)
            Wc[c2][kk] = *(const bf16x8*)&WT[((w * 2 + c2) * 16 + l16) * 128 + kk * 32 + lgrp * 8];
    const float* bb = bo + t * 128;
    f32x4 bv0 = *(const f32x4*)&bb[(w * 2 + 0) * 16 + lgrp * 4];
    f32x4 bv1 = *(const f32x4*)&bb[(w * 2 + 1) * 16 + lgrp * 4];
    f32x4 acc[8][2];
#pragma unroll
    for (int rt = 0; rt < 8; ++rt) { acc[rt][0] = bv0; acc[rt][1] = bv1; }
#pragma unroll
    for (int rt = 0; rt < 8; ++rt) {
#pragma unroll
        for (int kk = 0; kk < 4; ++kk) {
            bf16x8 xb = *(const bf16x8*)&Gs[(rt * 16 + l16) * 136 + kk * 32 + lgrp * 8];
            acc[rt][0] = __builtin_amdgcn_mfma_f32_16x16x32_bf16(Wc[0][kk], xb, acc[rt][0], 0, 0, 0);
            acc[rt][1] = __builtin_amdgcn_mfma_f32_16x16x32_bf16(Wc[1][kk], xb, acc[rt][1], 0, 0, 0);
        }
    }
    float a = 1.f / (1.f + expf(-skip[t]));
    // batch the 16 independent xsb loads, then blend/store
    short4v pv[8][2];
#pragma unroll
    for (int rt = 0; rt < 8; ++rt) {
        int node = n0 + rt * 16 + l16;
        size_t base = ((size_t)t * N + (size_t)(node < N ? node : 0)) * HD;
#pragma unroll
        for (int c2 = 0; c2 < 2; ++c2)
            pv[rt][c2] = *(const short4v*)((const unsigned short*)xsb + base + (w * 2 + c2) * 16 + lgrp * 4);
    }
#pragma unroll
    for (int rt = 0; rt < 8; ++rt) {
        int node = n0 + rt * 16 + l16;
        if (node < N) {
#pragma unroll
            for (int c2 = 0; c2 < 2; ++c2) {
                size_t idx = ((size_t)t * N + node) * HD + (w * 2 + c2) * 16 + lgrp * 4;
                f32x4 o;
#pragma unroll
                for (int j = 0; j < 4; ++j)
                    o[j] = fmaxf(a * acc[rt][c2][j] + (1.f - a) * bf2f((unsigned short)pv[rt][c2][j]), 0.f);
                *(f32x4*)&xs[idx] = o;
            }
        }
    }
}

extern "C" void kernel_launch(void* const* d_in, const int* in_sizes, int n_in,
                              void* d_out, int out_size, void* d_ws, size_t ws_size,
                              hipStream_t stream) {
    const float* x_region = (const float*)d_in[0];
    const float* x_site   = (const float*)d_in[1];
    const float* pWr  = (const float*)d_in[2];
    const float* pbr  = (const float*)d_in[3];
    const float* pWs  = (const float*)d_in[4];
    const float* pbs  = (const float*)d_in[5];
    const float* Wk   = (const float*)d_in[6];
    const float* bk   = (const float*)d_in[7];
    const float* Wq   = (const float*)d_in[8];
    const float* bq   = (const float*)d_in[9];
    const float* Wv   = (const float*)d_in[10];
    const float* bv   = (const float*)d_in[11];
    const float* Wo   = (const float*)d_in[12];
    const float* bo   = (const float*)d_in[13];
    const float* skip = (const float*)d_in[14];
    const float* Krel = (const float*)d_in[15];
    const float* Vrel = (const float*)d_in[16];
    const float* prel = (const float*)d_in[17];
    const int* e0 = (const int*)d_in[18];
    const int* e1 = (const int*)d_in[19];
    const int* e2 = (const int*)d_in[20];

    int N = in_sizes[0] / 64;   // 100000
    int E = in_sizes[18] / 2;   // 200000
    int nb0 = (N + 127) / 128;
    int N2 = 2 * N;

    float* xs = (float*)d_out;  // [2][N][128] fp32 — written once by the final out_gemm

    size_t NB = (size_t)N * HD;
    char* p = (char*)d_ws;
    bf16* q_bf  = (bf16*)p; p += 2 * NB * sizeof(bf16);          // [2][N][128]
    bf16* kv_bf = (bf16*)p; p += 3 * (size_t)N * 256 * sizeof(bf16); // [3][N][K(128)|V(128)]
    bf16* g_bf  = (bf16*)p; p += 2 * NB * sizeof(bf16);
    bf16* xsb   = (bf16*)p; p += 2 * NB * sizeof(bf16);          // bf16 node state (intermediate xs)
    int*  adj   = (int*)p;  p += (size_t)N2 * SLOTS * sizeof(int);
    int*  deg   = (int*)p;  p += (size_t)N2 * sizeof(int);
    bf16* PWrT  = (bf16*)p; p += 8192 * sizeof(bf16);            // [128][64]
    bf16* PWsT  = (bf16*)p; p += 4096 * sizeof(bf16);            // [128][32]
    bf16* Wall  = (bf16*)p; p += 2 * 8 * 16384 * sizeof(bf16);   // [L][8][128][128]
    bf16* WoT_a = (bf16*)p; p += 2 * 2 * 16384 * sizeof(bf16);   // [L][2][128][128]
    float* Ball = (float*)p; p += 2 * 8 * 128 * sizeof(float);   // [L][8][128]
    (void)ws_size; (void)n_in; (void)out_size;

    // ---- adjacency (edge lists are launch-constant) ----
    hipMemsetAsync(deg, 0, (size_t)N2 * sizeof(int), stream);
    int bgrid = (E + 255) / 256;
    build_adj<<<bgrid, 256, 0, stream>>>(e0, adj, deg, N, 0, E); // r2s -> dst type 1
    build_adj<<<bgrid, 256, 0, stream>>>(e1, adj, deg, 0, 1, E); // s2r -> dst type 0
    build_adj<<<bgrid, 256, 0, stream>>>(e2, adj, deg, N, 2, E); // s2s -> dst type 1

    // ---- weight prep ----
    transpose_bf16<<<32, 256, 0, stream>>>(pWr, PWrT, 64, 128, 64, 8192);
    transpose_bf16<<<16, 256, 0, stream>>>(pWs, PWsT, 32, 128, 32, 4096);
    for (int l = 0; l < 2; ++l) {
        transpose_bf16<<<128, 256, 0, stream>>>(Wq + (size_t)l * 2 * 16384,
                                                Wall + (size_t)l * 8 * 16384, 128, 128, 128, 32768);
        transpose_bf16<<<128, 256, 0, stream>>>(Wo + (size_t)l * 2 * 16384,
                                                WoT_a + (size_t)l * 2 * 16384, 128, 128, 128, 32768);
    }
    fuse_relw<<<768, 256, 0, stream>>>(Wk, Wv, Krel, Vrel, Wall);
    fuse_relb<<<8, 256, 0, stream>>>(bk, bv, bq, Krel, Vrel, Ball);

    int ggrid = (N2 * 32 + 255) / 256;

    // layer 0: fused proj + qkv (bf16 node state)
    proj_qkv<<<2 * nb0, 256, 0, stream>>>(
        x_region, x_site, PWrT, pbr, PWsT, pbs, xsb,
        Wall, Ball, q_bf, kv_bf, N, nb0);
    gather_kernel<<<ggrid, 256, 0, stream>>>(
        adj, deg, q_bf, kv_bf, prel, g_bf, N2, N);
    // layer seam: fused out(l0) + qkv(l1), bf16 state round-trip only
    out_qkv<<<2 * nb0, 256, 0, stream>>>(
        xsb, g_bf, WoT_a, bo, skip,
        Wall + (size_t)8 * 16384, Ball + 8 * 128, q_bf, kv_bf, N, nb0);
    gather_kernel<<<ggrid, 256, 0, stream>>>(
        adj, deg, q_bf, kv_bf, prel + 12, g_bf, N2, N);
    // final out (l1): blend vs bf16 prev, write fp32 d_out
    out_gemm<<<2 * nb0, 256, 0, stream>>>(
        xs, xsb, g_bf, WoT_a + (size_t)2 * 16384, bo + 2 * HD, skip + 2, N, nb0);
}

// Round 9
// 491.479 us; speedup vs baseline: 1.2375x; 1.0941x over previous
//
#include <hip/hip_runtime.h>
#include <hip/hip_bf16.h>

#define HD 128
#define H 4
#define D 32
#define SLOTS 64

typedef __hip_bfloat16 bf16;
typedef __attribute__((ext_vector_type(8))) short bf16x8;
typedef __attribute__((ext_vector_type(4))) float f32x4;
typedef __attribute__((ext_vector_type(4))) short short4v;

__device__ __forceinline__ float bf2f(unsigned short u) {
    union { unsigned int i; float f; } v; v.i = ((unsigned int)u) << 16; return v.f;
}
__device__ __forceinline__ short f2bf(float f) {
    union { float f; unsigned u; } v; v.f = f;
    unsigned r = v.u + 0x7fff + ((v.u >> 16) & 1);
    return (short)(r >> 16);
}
// HW packed fp32->bf16 (RNE), 2 values/instr
__device__ __forceinline__ short4v pack4(float a0, float a1, float a2, float a3) {
    union { unsigned u[2]; short4v v; } r;
    asm("v_cvt_pk_bf16_f32 %0, %1, %2" : "=v"(r.u[0]) : "v"(a0), "v"(a1));
    asm("v_cvt_pk_bf16_f32 %0, %1, %2" : "=v"(r.u[1]) : "v"(a2), "v"(a3));
    return r.v;
}
__device__ __forceinline__ bf16x8 pack8(const f32x4 lo, const f32x4 hi) {
    union { unsigned u[4]; bf16x8 v; } r;
    asm("v_cvt_pk_bf16_f32 %0, %1, %2" : "=v"(r.u[0]) : "v"(lo[0]), "v"(lo[1]));
    asm("v_cvt_pk_bf16_f32 %0, %1, %2" : "=v"(r.u[1]) : "v"(lo[2]), "v"(lo[3]));
    asm("v_cvt_pk_bf16_f32 %0, %1, %2" : "=v"(r.u[2]) : "v"(hi[0]), "v"(hi[1]));
    asm("v_cvt_pk_bf16_f32 %0, %1, %2" : "=v"(r.u[3]) : "v"(hi[2]), "v"(hi[3]));
    return r.v;
}
// 8-lane-group sum at VALU speed via DPP (quad_perm xor1, xor2, row_half_mirror).
__device__ __forceinline__ float dpp8_sum(float p) {
    union { int i; float f; } u, v;
    u.f = p;
    v.i = __builtin_amdgcn_mov_dpp(u.i, 0xB1, 0xF, 0xF, true);  p += v.f; u.f = p;  // quad_perm xor1
    v.i = __builtin_amdgcn_mov_dpp(u.i, 0x4E, 0xF, 0xF, true);  p += v.f; u.f = p;  // quad_perm xor2
    v.i = __builtin_amdgcn_mov_dpp(u.i, 0x141, 0xF, 0xF, true); p += v.f;           // row_half_mirror
    return p;
}

// ---------------- weight pre-transpose: dst[b][c][kd] = bf16(src[b][k][c]) ----------------
__global__ __launch_bounds__(256) void transpose_bf16(
    const float* __restrict__ src, bf16* __restrict__ dst, int K, int C, int Kd, int total) {
    int i = blockIdx.x * 256 + threadIdx.x;
    if (i >= total) return;
    int kd = i % Kd; int rem = i / Kd; int c = rem % C; int b = rem / C;
    float v = (kd < K) ? src[((size_t)b * K + kd) * C + c] : 0.f;
    ((unsigned short*)dst)[i] = (unsigned short)f2bf(v);
}

// ---------------- fuse relation transforms into k/v weights ----------------
__global__ __launch_bounds__(256) void fuse_relw(
    const float* __restrict__ Wk, const float* __restrict__ Wv,
    const float* __restrict__ Krel, const float* __restrict__ Vrel,
    bf16* __restrict__ Wall) {
    int gid = blockIdx.x * 256 + threadIdx.x;  // 12 * 16384
    int m = gid >> 14;
    int idx = gid & 16383;
    int ep = idx >> 7, i = idx & 127;
    int l = m / 6, kv = (m / 3) & 1, r = m % 3;
    int s = (r == 0) ? 0 : 1;
    const float* W = (kv ? Wv : Wk) + ((size_t)(l * 2 + s)) * 16384;
    const float* R = (kv ? Vrel : Krel) + ((size_t)(l * 3 + r)) * 4096;
    int h = ep >> 5, e = ep & 31;
    float acc = 0.f;
#pragma unroll
    for (int d = 0; d < 32; ++d)
        acc = fmaf(W[i * 128 + h * 32 + d], R[h * 1024 + d * 32 + e], acc);
    int slot = l * 8 + 2 + kv * 3 + r;
    ((unsigned short*)Wall)[(size_t)slot * 16384 + ep * 128 + i] = (unsigned short)f2bf(acc);
}

// Ball layout per layer: [8][128] fp32; slots 0,1 = bq; 2..4 fused bk; 5..7 fused bv
__global__ __launch_bounds__(256) void fuse_relb(
    const float* __restrict__ bk, const float* __restrict__ bv, const float* __restrict__ bq,
    const float* __restrict__ Krel, const float* __restrict__ Vrel,
    float* __restrict__ Ball) {
    int gid = blockIdx.x * 256 + threadIdx.x;  // 2048
    if (gid >= 2048) return;
    int col = gid & 127, m = gid >> 7;
    int l = m >> 3, g = m & 7;
    float val;
    if (g < 2) {
        val = bq[(l * 2 + g) * 128 + col];
    } else {
        int kv = (g - 2) / 3, r = (g - 2) % 3, s = (r == 0) ? 0 : 1;
        const float* b = (kv ? bv : bk) + (size_t)(l * 2 + s) * 128;
        const float* R = (kv ? Vrel : Krel) + (size_t)(l * 3 + r) * 4096;
        int h = col >> 5, e = col & 31;
        float acc = 0.f;
#pragma unroll
        for (int d = 0; d < 32; ++d)
            acc = fmaf(b[h * 32 + d], R[h * 1024 + d * 32 + e], acc);
        val = acc;
    }
    Ball[gid] = val;
}

// ---------------- adjacency build: fixed 64 slots per dst node ----------------
__global__ __launch_bounds__(256) void build_adj(
    const int* __restrict__ edge, int* __restrict__ adj, int* __restrict__ deg,
    int dstBase, int rel, int E) {
    int i = blockIdx.x * 256 + threadIdx.x;
    if (i >= E) return;
    int src = edge[i];
    int dst = edge[E + i];
    int slot = atomicAdd(deg + dstBase + dst, 1);
    if (slot < SLOTS) adj[(size_t)(dstBase + dst) * SLOTS + slot] = src | (rel << 20);
}

// ---------------- shared qkv slice phase with LDS store-staging ----------------
// Compute as before (acc[8][2] per wave), but bounce output through St[64][136] in two
// 64-node halves so global stores are 16B/thread, 256B-contiguous per node row (full 64B
// lines; q rows coalesce into 4KB bursts). Old path: 8B/lane at 512B stride = 16 distinct
// lines per quarter-wave with 8B each -> L2 write-sector bound (1.68 TB/s plateau, r4-r8).
__device__ __forceinline__ void qkv_phase(
    const short* Xs, short* St, const bf16* __restrict__ Wall, const float* __restrict__ Ball,
    bf16* __restrict__ qo, bf16* __restrict__ kvo,
    int t, int n0, int N, int w, int l16, int lgrp) {
    size_t NB = (size_t)N * HD;
    int tid = threadIdx.x;
    int nsl = t ? 5 : 3;
    unsigned list = t ? 0x76431u : 0x520u;  // slice ids, 4 bits each
    for (int si = 0; si < nsl; ++si) {
        int g = (list >> (4 * si)) & 15;
        const bf16* WT = Wall + (size_t)g * 16384;
        bf16x8 Wc[2][4];
#pragma unroll
        for (int c2 = 0; c2 < 2; ++c2)
#pragma unroll
            for (int kk = 0; kk < 4; ++kk)
                Wc[c2][kk] = *(const bf16x8*)&WT[((w * 2 + c2) * 16 + l16) * 128 + kk * 32 + lgrp * 8];
        const float* bb = Ball + g * 128;
        f32x4 bv0 = *(const f32x4*)&bb[(w * 2 + 0) * 16 + lgrp * 4];
        f32x4 bv1 = *(const f32x4*)&bb[(w * 2 + 1) * 16 + lgrp * 4];
        f32x4 acc[8][2];
#pragma unroll
        for (int rt = 0; rt < 8; ++rt) { acc[rt][0] = bv0; acc[rt][1] = bv1; }
#pragma unroll
        for (int rt = 0; rt < 8; ++rt) {
#pragma unroll
            for (int kk = 0; kk < 4; ++kk) {
                bf16x8 xb = *(const bf16x8*)&Xs[(rt * 16 + l16) * 136 + kk * 32 + lgrp * 8];
                acc[rt][0] = __builtin_amdgcn_mfma_f32_16x16x32_bf16(Wc[0][kk], xb, acc[rt][0], 0, 0, 0);
                acc[rt][1] = __builtin_amdgcn_mfma_f32_16x16x32_bf16(Wc[1][kk], xb, acc[rt][1], 0, 0, 0);
            }
        }
        // dest: q -> [g][node][128]; K/V -> interleaved [r][node][K|V] 256-elem records
        unsigned short* outp;
        int rowStride, off2;
        if (g < 2) {
            outp = (unsigned short*)(qo + (size_t)g * NB);
            rowStride = HD; off2 = 0;
        } else {
            int gi = g - 2, r = gi % 3, isV = gi / 3;
            outp = (unsigned short*)(kvo + (size_t)r * N * 256);
            rowStride = 256; off2 = isV * 128;
        }
        // staged store: two 64-node halves through St
#pragma unroll
        for (int half = 0; half < 2; ++half) {
            __syncthreads();  // St free (previous half's / slice's reads done)
#pragma unroll
            for (int q4 = 0; q4 < 4; ++q4) {
                int rt = half * 4 + q4;
#pragma unroll
                for (int c2 = 0; c2 < 2; ++c2) {
                    short4v s = pack4(acc[rt][c2][0], acc[rt][c2][1], acc[rt][c2][2], acc[rt][c2][3]);
                    *(short4v*)&St[(q4 * 16 + l16) * 136 + (w * 2 + c2) * 16 + lgrp * 4] = s;
                }
            }
            __syncthreads();
            // 256 threads x 16B x 4 iters = 16 KB; 16 threads cover one node's 256B row
#pragma unroll
            for (int j = 0; j < 4; ++j) {
                int flat = tid + j * 256;
                int nl = flat >> 4, c8 = flat & 15;
                int node = n0 + half * 64 + nl;
                if (node < N) {
                    bf16x8 v = *(const bf16x8*)&St[nl * 136 + c8 * 8];
                    *(bf16x8*)(outp + (size_t)node * rowStride + off2 + c8 * 8) = v;
                }
            }
        }
    }
}

// ---------------- fused: initial projection (bf16 state out) + layer-0 qkv ----------------
__global__ __launch_bounds__(256) void proj_qkv(
    const float* __restrict__ xr, const float* __restrict__ xsi,
    const bf16* __restrict__ WrT, const float* __restrict__ br,
    const bf16* __restrict__ WsT, const float* __restrict__ bs,
    bf16* __restrict__ xsb,
    const bf16* __restrict__ Wall, const float* __restrict__ Ball,
    bf16* __restrict__ qo, bf16* __restrict__ kvo, int N, int nb0) {
    __shared__ short Xs[128 * 136];
    __shared__ short St[64 * 136];
    int b = blockIdx.x;
    int t = b < nb0 ? 1 : 0;
    int blk = t ? b : b - nb0;
    int tid = threadIdx.x;
    int w = tid >> 6, lane = tid & 63, l16 = lane & 15, lgrp = lane >> 4;
    int n0 = blk * 128;
    int rowbase = n0 + w * 32;
    int K = t ? 32 : 64;
    const float* X = t ? xsi : xr;
    const bf16* WT = t ? WsT : WrT;  // [128][K]
    const float* bb = t ? bs : br;
    f32x4 acc[2][8];
#pragma unroll
    for (int c = 0; c < 8; ++c) {
        f32x4 bv = *(const f32x4*)&bb[c * 16 + lgrp * 4];
        acc[0][c] = bv; acc[1][c] = bv;
    }
    int r0 = rowbase + l16, r1 = rowbase + 16 + l16;
    bool v0 = r0 < N, v1 = r1 < N;
    size_t b0 = (size_t)(v0 ? r0 : 0) * K, b1 = (size_t)(v1 ? r1 : 0) * K;
    int nkk = K >> 5;
    for (int kk = 0; kk < nkk; ++kk) {
        int ko = kk * 32 + lgrp * 8;
        f32x4 lo0 = {0,0,0,0}, hi0 = {0,0,0,0}, lo1 = {0,0,0,0}, hi1 = {0,0,0,0};
        if (v0) { lo0 = *(const f32x4*)&X[b0 + ko]; hi0 = *(const f32x4*)&X[b0 + ko + 4]; }
        if (v1) { lo1 = *(const f32x4*)&X[b1 + ko]; hi1 = *(const f32x4*)&X[b1 + ko + 4]; }
        bf16x8 x0 = pack8(lo0, hi0);
        bf16x8 x1 = pack8(lo1, hi1);
#pragma unroll
        for (int c = 0; c < 8; ++c) {
            bf16x8 wa = *(const bf16x8*)&WT[(size_t)(c * 16 + l16) * K + ko];
            acc[0][c] = __builtin_amdgcn_mfma_f32_16x16x32_bf16(wa, x0, acc[0][c], 0, 0, 0);
            acc[1][c] = __builtin_amdgcn_mfma_f32_16x16x32_bf16(wa, x1, acc[1][c], 0, 0, 0);
        }
    }
    // epilogue: write bf16 state + stage bf16 tile to LDS (row = tile-local node)
#pragma unroll
    for (int nt = 0; nt < 2; ++nt) {
        int lrow = w * 32 + nt * 16 + l16;
        int node = n0 + lrow;
        bool vn = node < N;
#pragma unroll
        for (int c = 0; c < 8; ++c) {
            int col = c * 16 + lgrp * 4;
            short4v s = pack4(acc[nt][c][0], acc[nt][c][1], acc[nt][c][2], acc[nt][c][3]);
            if (vn) *(short4v*)((unsigned short*)xsb + ((size_t)t * N + node) * HD + col) = s;
            *(short4v*)&Xs[lrow * 136 + col] = s;
        }
    }
    __syncthreads();
    qkv_phase(Xs, St, Wall, Ball, qo, kvo, t, n0, N, w, l16, lgrp);
}

// ------------- dst-centric gather: interleaved K|V records, width-32 shfl, 2-deep pipeline -------------
__global__ __launch_bounds__(256) void gather_kernel(
    const int* __restrict__ adj, const int* __restrict__ deg,
    const bf16* __restrict__ q, const bf16* __restrict__ kv,
    const float* __restrict__ prel, bf16* __restrict__ g, int N2, int N) {
    int grp = (blockIdx.x * 256 + threadIdx.x) >> 5;  // node in [0, 2N)
    int lane = threadIdx.x & 31;
    if (grp >= N2) return;
    int h = lane >> 3;

    ushort4 qa = *((const ushort4*)(q + (size_t)grp * HD) + lane);
    float q0 = bf2f(qa.x), q1 = bf2f(qa.y), q2 = bf2f(qa.z), q3 = bf2f(qa.w);
    const float is = 0.17677669529663687f; // 1/sqrt(32)
    float pr0 = prel[0 * H + h] * is, pr1 = prel[1 * H + h] * is, pr2 = prel[2 * H + h] * is;

    float m0 = 0.f, m1 = 0.f, m2 = 0.f, m3 = 0.f, dacc = 0.f;
    int dg = deg[grp]; if (dg > SLOTS) dg = SLOTS;
    const int* lst = adj + (size_t)grp * SLOTS;
    int myeA = (lane < dg) ? lst[lane] : 0;
    int myeB = (lane + 32 < dg) ? lst[lane + 32] : 0;

    if (dg > 0) {
        int ecur = __shfl(myeA, 0, 32);
        const bf16* base = kv + ((size_t)(ecur >> 20) * N + (ecur & 0xFFFFF)) * 256;
        ushort4 ka = *((const ushort4*)base + lane);
        ushort4 va = *((const ushort4*)base + 32 + lane);
        for (int i = 0; i < dg; ++i) {
            int en = 0;
            ushort4 kan = {0, 0, 0, 0}, van = {0, 0, 0, 0};
            if (i + 1 < dg) {  // prefetch next edge's record before processing current
                en = (i + 1 < 32) ? __shfl(myeA, i + 1, 32) : __shfl(myeB, i + 1 - 32, 32);
                const bf16* basen = kv + ((size_t)(en >> 20) * N + (en & 0xFFFFF)) * 256;
                kan = *((const ushort4*)basen + lane);
                van = *((const ushort4*)basen + 32 + lane);
            }
            int r = ecur >> 20;
            float p = q0 * bf2f(ka.x) + q1 * bf2f(ka.y) + q2 * bf2f(ka.z) + q3 * bf2f(ka.w);
            p = dpp8_sum(p);  // 8-lane head reduce at VALU speed
            float prv = (r == 0) ? pr0 : ((r == 1) ? pr1 : pr2);
            float eh = __expf(p * prv); // max-subtraction dropped: mathematically identical
            m0 = fmaf(eh, bf2f(va.x), m0);
            m1 = fmaf(eh, bf2f(va.y), m1);
            m2 = fmaf(eh, bf2f(va.z), m2);
            m3 = fmaf(eh, bf2f(va.w), m3);
            dacc += eh;
            ecur = en; ka = kan; va = van;
        }
    }
    float inv = dacc > 0.f ? 1.f / dacc : 0.f;
    const float c = 0.70710678118654752f;
    float v0 = m0 * inv, v1 = m1 * inv, v2 = m2 * inv, v3 = m3 * inv;
    float g0 = 0.5f * v0 * (1.f + erff(v0 * c));
    float g1 = 0.5f * v1 * (1.f + erff(v1 * c));
    float g2 = 0.5f * v2 * (1.f + erff(v2 * c));
    float g3 = 0.5f * v3 * (1.f + erff(v3 * c));
    *((short4v*)(g + (size_t)grp * HD) + lane) = pack4(g0, g1, g2, g3);
}

// ------------- fused: out GEMM (layer l, bf16 state) + qkv (layer l+1); t1 first -------------
__global__ __launch_bounds__(256) void out_qkv(
    bf16* __restrict__ xsb, const bf16* __restrict__ gbuf,
    const bf16* __restrict__ WoT, const float* __restrict__ bo,
    const float* __restrict__ skip,
    const bf16* __restrict__ Wall, const float* __restrict__ Ball,
    bf16* __restrict__ qo, bf16* __restrict__ kvo, int N, int nb0) {
    __shared__ short S[128 * 136];
    __shared__ short St[64 * 136];
    int b = blockIdx.x;
    int t = b < nb0 ? 1 : 0;
    int blk = t ? b : b - nb0;
    int tid = threadIdx.x;
    int w = tid >> 6, lane = tid & 63, l16 = lane & 15, lgrp = lane >> 4;
    int n0 = blk * 128;
    size_t NB = (size_t)N * HD;
    const bf16* G = gbuf + (size_t)t * NB;
#pragma unroll
    for (int j = 0; j < 8; ++j) {
        int flat = tid + j * 256;
        int row = flat >> 4, c16 = flat & 15;
        bf16x8 v = {0, 0, 0, 0, 0, 0, 0, 0};
        if (n0 + row < N) v = *(const bf16x8*)&G[(size_t)(n0 + row) * HD + c16 * 8];
        *(bf16x8*)&S[row * 136 + c16 * 8] = v;
    }
    __syncthreads();
    const bf16* WT = WoT + (size_t)t * 16384;
    bf16x8 Wc[2][4];
#pragma unroll
    for (int c2 = 0; c2 < 2; ++c2)
#pragma unroll
        for (int kk = 0; kk < 4; ++kk)
            Wc[c2][kk] = *(const bf16x8*)&WT[((w * 2 + c2) * 16 + l16) * 128 + kk * 32 + lgrp * 8];
    const float* bb = bo + t * 128;
    f32x4 bv0 = *(const f32x4*)&bb[(w * 2 + 0) * 16 + lgrp * 4];
    f32x4 bv1 = *(const f32x4*)&bb[(w * 2 + 1) * 16 + lgrp * 4];
    f32x4 acc[8][2];
#pragma unroll
    for (int rt = 0; rt < 8; ++rt) { acc[rt][0] = bv0; acc[rt][1] = bv1; }
#pragma unroll
    for (int rt = 0; rt < 8; ++rt) {
#pragma unroll
        for (int kk = 0; kk < 4; ++kk) {
            bf16x8 xb = *(const bf16x8*)&S[(rt * 16 + l16) * 136 + kk * 32 + lgrp * 8];
            acc[rt][0] = __builtin_amdgcn_mfma_f32_16x16x32_bf16(Wc[0][kk], xb, acc[rt][0], 0, 0, 0);
            acc[rt][1] = __builtin_amdgcn_mfma_f32_16x16x32_bf16(Wc[1][kk], xb, acc[rt][1], 0, 0, 0);
        }
    }
    float a = 1.f / (1.f + expf(-skip[t]));
    // batch all 16 independent xsb loads before the barrier (latency under barrier wait)
    short4v pv[8][2];
#pragma unroll
    for (int rt = 0; rt < 8; ++rt) {
        int node = n0 + rt * 16 + l16;
        size_t base = ((size_t)t * N + (size_t)(node < N ? node : 0)) * HD;
#pragma unroll
        for (int c2 = 0; c2 < 2; ++c2)
            pv[rt][c2] = *(const short4v*)((const unsigned short*)xsb + base + (w * 2 + c2) * 16 + lgrp * 4);
    }
    __syncthreads();  // all reads of S done; safe to overwrite with the new tile
#pragma unroll
    for (int rt = 0; rt < 8; ++rt) {
        int lrow = rt * 16 + l16;
        int node = n0 + lrow;
        bool vn = node < N;
#pragma unroll
        for (int c2 = 0; c2 < 2; ++c2) {
            int col = (w * 2 + c2) * 16 + lgrp * 4;
            short4v s;
            if (vn) {
                size_t idx = ((size_t)t * N + node) * HD + col;
                f32x4 o;
#pragma unroll
                for (int j = 0; j < 4; ++j)
                    o[j] = fmaxf(a * acc[rt][c2][j] + (1.f - a) * bf2f((unsigned short)pv[rt][c2][j]), 0.f);
                s = pack4(o[0], o[1], o[2], o[3]);
                *(short4v*)((unsigned short*)xsb + idx) = s;
            } else {
                s = (short4v){0, 0, 0, 0};
            }
            *(short4v*)&S[lrow * 136 + col] = s;
        }
    }
    __syncthreads();
    qkv_phase(S, St, Wall, Ball, qo, kvo, t, n0, N, w, l16, lgrp);
}

// ------------- final output: G tile in LDS; skip blend vs bf16 prev, ReLU, fp32 d_out -------------
// Output staged through Gs (free after MFMA) in two 64-node fp32 halves -> fully
// contiguous 16B/thread stores (4KB bursts) instead of 16B at 512B stride.
__global__ __launch_bounds__(256) void out_gemm(
    float* __restrict__ xs, const bf16* __restrict__ xsb, const bf16* __restrict__ gbuf,
    const bf16* __restrict__ WoT, const float* __restrict__ bo,
    const float* __restrict__ skip, int N, int nb0) {
    __shared__ short Gs[128 * 136];
    float* Gf = (float*)Gs;  // fp32 staging view [64][132] = 33792 B <= 34816 B
    int b = blockIdx.x;
    int t = b >= nb0 ? 1 : 0;
    int blk = t ? b - nb0 : b;
    int tid = threadIdx.x;
    int w = tid >> 6, lane = tid & 63, l16 = lane & 15, lgrp = lane >> 4;
    int n0 = blk * 128;
    size_t NB = (size_t)N * HD;
    const bf16* G = gbuf + (size_t)t * NB;
#pragma unroll
    for (int j = 0; j < 8; ++j) {
        int flat = tid + j * 256;
        int row = flat >> 4, c16 = flat & 15;
        bf16x8 v = {0, 0, 0, 0, 0, 0, 0, 0};
        if (n0 + row < N) v = *(const bf16x8*)&G[(size_t)(n0 + row) * HD + c16 * 8];
        *(bf16x8*)&Gs[row * 136 + c16 * 8] = v;
    }
    __syncthreads();
    const bf16* WT = WoT + (size_t)t * 16384;
    bf16x8 Wc[2][4];
#pragma unroll
    for (int c2 = 0; c2 < 2; ++c2)
#pragma unroll
        for (int kk = 0; kk < 4; ++kk)
            Wc[c2][kk] = *(const bf16x8*)&WT[((w * 2 + c2) * 16 + l16) * 128 + kk * 32 + lgrp * 8];
    const float* bb = bo + t * 128;
    f32x4 bv0 = *(const f32x4*)&bb[(w * 2 + 0) * 16 + lgrp * 4];
    f32x4 bv1 = *(const f32x4*)&bb[(w * 2 + 1) * 16 + lgrp * 4];
    f32x4 acc[8][2];
#pragma unroll
    for (int rt = 0; rt < 8; ++rt) { acc[rt][0] = bv0; acc[rt][1] = bv1; }
#pragma unroll
    for (int rt = 0; rt < 8; ++rt) {
#pragma unroll
        for (int kk = 0; kk < 4; ++kk) {
            bf16x8 xb = *(const bf16x8*)&Gs[(rt * 16 + l16) * 136 + kk * 32 + lgrp * 8];
            acc[rt][0] = __builtin_amdgcn_mfma_f32_16x16x32_bf16(Wc[0][kk], xb, acc[rt][0], 0, 0, 0);
            acc[rt][1] = __builtin_amdgcn_mfma_f32_16x16x32_bf16(Wc[1][kk], xb, acc[rt][1], 0, 0, 0);
        }
    }
    float a = 1.f / (1.f + expf(-skip[t]));
    // batch the 16 independent xsb loads (blend inputs)
    short4v pv[8][2];
#pragma unroll
    for (int rt = 0; rt < 8; ++rt) {
        int node = n0 + rt * 16 + l16;
        size_t base = ((size_t)t * N + (size_t)(node < N ? node : 0)) * HD;
#pragma unroll
        for (int c2 = 0; c2 < 2; ++c2)
            pv[rt][c2] = *(const short4v*)((const unsigned short*)xsb + base + (w * 2 + c2) * 16 + lgrp * 4);
    }
    // staged fp32 output: two 64-node halves through Gf
#pragma unroll
    for (int half = 0; half < 2; ++half) {
        __syncthreads();  // Gs MFMA reads (half 0) / previous half's stores (half 1) done
#pragma unroll
        for (int q4 = 0; q4 < 4; ++q4) {
            int rt = half * 4 + q4;
#pragma unroll
            for (int c2 = 0; c2 < 2; ++c2) {
                f32x4 o;
#pragma unroll
                for (int j = 0; j < 4; ++j)
                    o[j] = fmaxf(a * acc[rt][c2][j] + (1.f - a) * bf2f((unsigned short)pv[rt][c2][j]), 0.f);
                *(f32x4*)&Gf[(q4 * 16 + l16) * 132 + (w * 2 + c2) * 16 + lgrp * 4] = o;
            }
        }
        __syncthreads();
        // 256 threads x 16B x 8 iters = 32 KB; 32 threads cover one node's 512B row
#pragma unroll
        for (int j = 0; j < 8; ++j) {
            int flat = tid + j * 256;
            int nl = flat >> 5, c16 = flat & 31;
            int node = n0 + half * 64 + nl;
            if (node < N) {
                f32x4 v = *(const f32x4*)&Gf[nl * 132 + c16 * 4];
                *(f32x4*)&xs[((size_t)t * N + node) * HD + c16 * 4] = v;
            }
        }
    }
}

extern "C" void kernel_launch(void* const* d_in, const int* in_sizes, int n_in,
                              void* d_out, int out_size, void* d_ws, size_t ws_size,
                              hipStream_t stream) {
    const float* x_region = (const float*)d_in[0];
    const float* x_site   = (const float*)d_in[1];
    const float* pWr  = (const float*)d_in[2];
    const float* pbr  = (const float*)d_in[3];
    const float* pWs  = (const float*)d_in[4];
    const float* pbs  = (const float*)d_in[5];
    const float* Wk   = (const float*)d_in[6];
    const float* bk   = (const float*)d_in[7];
    const float* Wq   = (const float*)d_in[8];
    const float* bq   = (const float*)d_in[9];
    const float* Wv   = (const float*)d_in[10];
    const float* bv   = (const float*)d_in[11];
    const float* Wo   = (const float*)d_in[12];
    const float* bo   = (const float*)d_in[13];
    const float* skip = (const float*)d_in[14];
    const float* Krel = (const float*)d_in[15];
    const float* Vrel = (const float*)d_in[16];
    const float* prel = (const float*)d_in[17];
    const int* e0 = (const int*)d_in[18];
    const int* e1 = (const int*)d_in[19];
    const int* e2 = (const int*)d_in[20];

    int N = in_sizes[0] / 64;   // 100000
    int E = in_sizes[18] / 2;   // 200000
    int nb0 = (N + 127) / 128;
    int N2 = 2 * N;

    float* xs = (float*)d_out;  // [2][N][128] fp32 — written once by the final out_gemm

    size_t NB = (size_t)N * HD;
    char* p = (char*)d_ws;
    bf16* q_bf  = (bf16*)p; p += 2 * NB * sizeof(bf16);          // [2][N][128]
    bf16* kv_bf = (bf16*)p; p += 3 * (size_t)N * 256 * sizeof(bf16); // [3][N][K(128)|V(128)]
    bf16* g_bf  = (bf16*)p; p += 2 * NB * sizeof(bf16);
    bf16* xsb   = (bf16*)p; p += 2 * NB * sizeof(bf16);          // bf16 node state (intermediate xs)
    int*  adj   = (int*)p;  p += (size_t)N2 * SLOTS * sizeof(int);
    int*  deg   = (int*)p;  p += (size_t)N2 * sizeof(int);
    bf16* PWrT  = (bf16*)p; p += 8192 * sizeof(bf16);            // [128][64]
    bf16* PWsT  = (bf16*)p; p += 4096 * sizeof(bf16);            // [128][32]
    bf16* Wall  = (bf16*)p; p += 2 * 8 * 16384 * sizeof(bf16);   // [L][8][128][128]
    bf16* WoT_a = (bf16*)p; p += 2 * 2 * 16384 * sizeof(bf16);   // [L][2][128][128]
    float* Ball = (float*)p; p += 2 * 8 * 128 * sizeof(float);   // [L][8][128]
    (void)ws_size; (void)n_in; (void)out_size;

    // ---- adjacency (edge lists are launch-constant) ----
    hipMemsetAsync(deg, 0, (size_t)N2 * sizeof(int), stream);
    int bgrid = (E + 255) / 256;
    build_adj<<<bgrid, 256, 0, stream>>>(e0, adj, deg, N, 0, E); // r2s -> dst type 1
    build_adj<<<bgrid, 256, 0, stream>>>(e1, adj, deg, 0, 1, E); // s2r -> dst type 0
    build_adj<<<bgrid, 256, 0, stream>>>(e2, adj, deg, N, 2, E); // s2s -> dst type 1

    // ---- weight prep ----
    transpose_bf16<<<32, 256, 0, stream>>>(pWr, PWrT, 64, 128, 64, 8192);
    transpose_bf16<<<16, 256, 0, stream>>>(pWs, PWsT, 32, 128, 32, 4096);
    for (int l = 0; l < 2; ++l) {
        transpose_bf16<<<128, 256, 0, stream>>>(Wq + (size_t)l * 2 * 16384,
                                                Wall + (size_t)l * 8 * 16384, 128, 128, 128, 32768);
        transpose_bf16<<<128, 256, 0, stream>>>(Wo + (size_t)l * 2 * 16384,
                                                WoT_a + (size_t)l * 2 * 16384, 128, 128, 128, 32768);
    }
    fuse_relw<<<768, 256, 0, stream>>>(Wk, Wv, Krel, Vrel, Wall);
    fuse_relb<<<8, 256, 0, stream>>>(bk, bv, bq, Krel, Vrel, Ball);

    int ggrid = (N2 * 32 + 255) / 256;

    // layer 0: fused proj + qkv (bf16 node state)
    proj_qkv<<<2 * nb0, 256, 0, stream>>>(
        x_region, x_site, PWrT, pbr, PWsT, pbs, xsb,
        Wall, Ball, q_bf, kv_bf, N, nb0);
    gather_kernel<<<ggrid, 256, 0, stream>>>(
        adj, deg, q_bf, kv_bf, prel, g_bf, N2, N);
    // layer seam: fused out(l0) + qkv(l1), bf16 state round-trip only
    out_qkv<<<2 * nb0, 256, 0, stream>>>(
        xsb, g_bf, WoT_a, bo, skip,
        Wall + (size_t)8 * 16384, Ball + 8 * 128, q_bf, kv_bf, N, nb0);
    gather_kernel<<<ggrid, 256, 0, stream>>>(
        adj, deg, q_bf, kv_bf, prel + 12, g_bf, N2, N);
    // final out (l1): blend vs bf16 prev, write fp32 d_out
    out_gemm<<<2 * nb0, 256, 0, stream>>>(
        xs, xsb, g_bf, WoT_a + (size_t)2 * 16384, bo + 2 * HD, skip + 2, N, nb0);
}

// Round 10
// 475.341 us; speedup vs baseline: 1.2795x; 1.0340x over previous
//
#include <hip/hip_runtime.h>
#include <hip/hip_bf16.h>

#define HD 128
#define H 4
#define D 32
#define SLOTS 64

typedef __hip_bfloat16 bf16;
typedef __attribute__((ext_vector_type(8))) short bf16x8;
typedef __attribute__((ext_vector_type(4))) float f32x4;
typedef __attribute__((ext_vector_type(4))) short short4v;

__device__ __forceinline__ float bf2f(unsigned short u) {
    union { unsigned int i; float f; } v; v.i = ((unsigned int)u) << 16; return v.f;
}
__device__ __forceinline__ short f2bf(float f) {
    union { float f; unsigned u; } v; v.f = f;
    unsigned r = v.u + 0x7fff + ((v.u >> 16) & 1);
    return (short)(r >> 16);
}
// HW packed fp32->bf16 (RNE), 2 values/instr
__device__ __forceinline__ short4v pack4(float a0, float a1, float a2, float a3) {
    union { unsigned u[2]; short4v v; } r;
    asm("v_cvt_pk_bf16_f32 %0, %1, %2" : "=v"(r.u[0]) : "v"(a0), "v"(a1));
    asm("v_cvt_pk_bf16_f32 %0, %1, %2" : "=v"(r.u[1]) : "v"(a2), "v"(a3));
    return r.v;
}
__device__ __forceinline__ bf16x8 pack8(const f32x4 lo, const f32x4 hi) {
    union { unsigned u[4]; bf16x8 v; } r;
    asm("v_cvt_pk_bf16_f32 %0, %1, %2" : "=v"(r.u[0]) : "v"(lo[0]), "v"(lo[1]));
    asm("v_cvt_pk_bf16_f32 %0, %1, %2" : "=v"(r.u[1]) : "v"(lo[2]), "v"(lo[3]));
    asm("v_cvt_pk_bf16_f32 %0, %1, %2" : "=v"(r.u[2]) : "v"(hi[0]), "v"(hi[1]));
    asm("v_cvt_pk_bf16_f32 %0, %1, %2" : "=v"(r.u[3]) : "v"(hi[2]), "v"(hi[3]));
    return r.v;
}
// 8-lane-group sum at VALU speed via DPP (quad_perm xor1, xor2, row_half_mirror).
__device__ __forceinline__ float dpp8_sum(float p) {
    union { int i; float f; } u, v;
    u.f = p;
    v.i = __builtin_amdgcn_mov_dpp(u.i, 0xB1, 0xF, 0xF, true);  p += v.f; u.f = p;  // quad_perm xor1
    v.i = __builtin_amdgcn_mov_dpp(u.i, 0x4E, 0xF, 0xF, true);  p += v.f; u.f = p;  // quad_perm xor2
    v.i = __builtin_amdgcn_mov_dpp(u.i, 0x141, 0xF, 0xF, true); p += v.f;           // row_half_mirror
    return p;
}

// ---------------- weight pre-transpose: dst[b][c][kd] = bf16(src[b][k][c]) ----------------
__global__ __launch_bounds__(256) void transpose_bf16(
    const float* __restrict__ src, bf16* __restrict__ dst, int K, int C, int Kd, int total) {
    int i = blockIdx.x * 256 + threadIdx.x;
    if (i >= total) return;
    int kd = i % Kd; int rem = i / Kd; int c = rem % C; int b = rem / C;
    float v = (kd < K) ? src[((size_t)b * K + kd) * C + c] : 0.f;
    ((unsigned short*)dst)[i] = (unsigned short)f2bf(v);
}

// ---------------- fuse relation transforms into k/v weights ----------------
__global__ __launch_bounds__(256) void fuse_relw(
    const float* __restrict__ Wk, const float* __restrict__ Wv,
    const float* __restrict__ Krel, const float* __restrict__ Vrel,
    bf16* __restrict__ Wall) {
    int gid = blockIdx.x * 256 + threadIdx.x;  // 12 * 16384
    int m = gid >> 14;
    int idx = gid & 16383;
    int ep = idx >> 7, i = idx & 127;
    int l = m / 6, kv = (m / 3) & 1, r = m % 3;
    int s = (r == 0) ? 0 : 1;
    const float* W = (kv ? Wv : Wk) + ((size_t)(l * 2 + s)) * 16384;
    const float* R = (kv ? Vrel : Krel) + ((size_t)(l * 3 + r)) * 4096;
    int h = ep >> 5, e = ep & 31;
    float acc = 0.f;
#pragma unroll
    for (int d = 0; d < 32; ++d)
        acc = fmaf(W[i * 128 + h * 32 + d], R[h * 1024 + d * 32 + e], acc);
    int slot = l * 8 + 2 + kv * 3 + r;
    ((unsigned short*)Wall)[(size_t)slot * 16384 + ep * 128 + i] = (unsigned short)f2bf(acc);
}

// Ball layout per layer: [8][128] fp32; slots 0,1 = bq; 2..4 fused bk; 5..7 fused bv
__global__ __launch_bounds__(256) void fuse_relb(
    const float* __restrict__ bk, const float* __restrict__ bv, const float* __restrict__ bq,
    const float* __restrict__ Krel, const float* __restrict__ Vrel,
    float* __restrict__ Ball) {
    int gid = blockIdx.x * 256 + threadIdx.x;  // 2048
    if (gid >= 2048) return;
    int col = gid & 127, m = gid >> 7;
    int l = m >> 3, g = m & 7;
    float val;
    if (g < 2) {
        val = bq[(l * 2 + g) * 128 + col];
    } else {
        int kv = (g - 2) / 3, r = (g - 2) % 3, s = (r == 0) ? 0 : 1;
        const float* b = (kv ? bv : bk) + (size_t)(l * 2 + s) * 128;
        const float* R = (kv ? Vrel : Krel) + (size_t)(l * 3 + r) * 4096;
        int h = col >> 5, e = col & 31;
        float acc = 0.f;
#pragma unroll
        for (int d = 0; d < 32; ++d)
            acc = fmaf(b[h * 32 + d], R[h * 1024 + d * 32 + e], acc);
        val = acc;
    }
    Ball[gid] = val;
}

// ---------------- adjacency build: fixed 64 slots per dst node ----------------
__global__ __launch_bounds__(256) void build_adj(
    const int* __restrict__ edge, int* __restrict__ adj, int* __restrict__ deg,
    int dstBase, int rel, int E) {
    int i = blockIdx.x * 256 + threadIdx.x;
    if (i >= E) return;
    int src = edge[i];
    int dst = edge[E + i];
    int slot = atomicAdd(deg + dstBase + dst, 1);
    if (slot < SLOTS) adj[(size_t)(dstBase + dst) * SLOTS + slot] = src | (rel << 20);
}

// ---------------- shared qkv slice phase with LDS store-staging ----------------
// Compute as before (acc[8][2] per wave), but bounce output through St[64][136] in two
// 64-node halves so global stores are 16B/thread, 256B-contiguous per node row (full 64B
// lines; q rows coalesce into 4KB bursts). r9: this lifted out_qkv 151->120us.
__device__ __forceinline__ void qkv_phase(
    const short* Xs, short* St, const bf16* __restrict__ Wall, const float* __restrict__ Ball,
    bf16* __restrict__ qo, bf16* __restrict__ kvo,
    int t, int n0, int N, int w, int l16, int lgrp) {
    size_t NB = (size_t)N * HD;
    int tid = threadIdx.x;
    int nsl = t ? 5 : 3;
    unsigned list = t ? 0x76431u : 0x520u;  // slice ids, 4 bits each
    for (int si = 0; si < nsl; ++si) {
        int g = (list >> (4 * si)) & 15;
        const bf16* WT = Wall + (size_t)g * 16384;
        bf16x8 Wc[2][4];
#pragma unroll
        for (int c2 = 0; c2 < 2; ++c2)
#pragma unroll
            for (int kk = 0; kk < 4; ++kk)
                Wc[c2][kk] = *(const bf16x8*)&WT[((w * 2 + c2) * 16 + l16) * 128 + kk * 32 + lgrp * 8];
        const float* bb = Ball + g * 128;
        f32x4 bv0 = *(const f32x4*)&bb[(w * 2 + 0) * 16 + lgrp * 4];
        f32x4 bv1 = *(const f32x4*)&bb[(w * 2 + 1) * 16 + lgrp * 4];
        f32x4 acc[8][2];
#pragma unroll
        for (int rt = 0; rt < 8; ++rt) { acc[rt][0] = bv0; acc[rt][1] = bv1; }
#pragma unroll
        for (int rt = 0; rt < 8; ++rt) {
#pragma unroll
            for (int kk = 0; kk < 4; ++kk) {
                bf16x8 xb = *(const bf16x8*)&Xs[(rt * 16 + l16) * 136 + kk * 32 + lgrp * 8];
                acc[rt][0] = __builtin_amdgcn_mfma_f32_16x16x32_bf16(Wc[0][kk], xb, acc[rt][0], 0, 0, 0);
                acc[rt][1] = __builtin_amdgcn_mfma_f32_16x16x32_bf16(Wc[1][kk], xb, acc[rt][1], 0, 0, 0);
            }
        }
        // dest: q -> [g][node][128]; K/V -> interleaved [r][node][K|V] 256-elem records
        unsigned short* outp;
        int rowStride, off2;
        if (g < 2) {
            outp = (unsigned short*)(qo + (size_t)g * NB);
            rowStride = HD; off2 = 0;
        } else {
            int gi = g - 2, r = gi % 3, isV = gi / 3;
            outp = (unsigned short*)(kvo + (size_t)r * N * 256);
            rowStride = 256; off2 = isV * 128;
        }
        // staged store: two 64-node halves through St
#pragma unroll
        for (int half = 0; half < 2; ++half) {
            __syncthreads();  // St free (previous half's / slice's reads done)
#pragma unroll
            for (int q4 = 0; q4 < 4; ++q4) {
                int rt = half * 4 + q4;
#pragma unroll
                for (int c2 = 0; c2 < 2; ++c2) {
                    short4v s = pack4(acc[rt][c2][0], acc[rt][c2][1], acc[rt][c2][2], acc[rt][c2][3]);
                    *(short4v*)&St[(q4 * 16 + l16) * 136 + (w * 2 + c2) * 16 + lgrp * 4] = s;
                }
            }
            __syncthreads();
            // 256 threads x 16B x 4 iters = 16 KB; 16 threads cover one node's 256B row
#pragma unroll
            for (int j = 0; j < 4; ++j) {
                int flat = tid + j * 256;
                int nl = flat >> 4, c8 = flat & 15;
                int node = n0 + half * 64 + nl;
                if (node < N) {
                    bf16x8 v = *(const bf16x8*)&St[nl * 136 + c8 * 8];
                    *(bf16x8*)(outp + (size_t)node * rowStride + off2 + c8 * 8) = v;
                }
            }
        }
    }
}

// ---------------- fused: initial projection (bf16 state out) + layer-0 qkv ----------------
// xsb store now a contiguous Xs->xsb pass (state tile is already staged in Xs) —
// the old scattered 8B/lane store was the same write-sector pattern r9 eliminated.
__global__ __launch_bounds__(256) void proj_qkv(
    const float* __restrict__ xr, const float* __restrict__ xsi,
    const bf16* __restrict__ WrT, const float* __restrict__ br,
    const bf16* __restrict__ WsT, const float* __restrict__ bs,
    bf16* __restrict__ xsb,
    const bf16* __restrict__ Wall, const float* __restrict__ Ball,
    bf16* __restrict__ qo, bf16* __restrict__ kvo, int N, int nb0) {
    __shared__ short Xs[128 * 136];
    __shared__ short St[64 * 136];
    int b = blockIdx.x;
    int t = b < nb0 ? 1 : 0;
    int blk = t ? b : b - nb0;
    int tid = threadIdx.x;
    int w = tid >> 6, lane = tid & 63, l16 = lane & 15, lgrp = lane >> 4;
    int n0 = blk * 128;
    int rowbase = n0 + w * 32;
    int K = t ? 32 : 64;
    const float* X = t ? xsi : xr;
    const bf16* WT = t ? WsT : WrT;  // [128][K]
    const float* bb = t ? bs : br;
    f32x4 acc[2][8];
#pragma unroll
    for (int c = 0; c < 8; ++c) {
        f32x4 bv = *(const f32x4*)&bb[c * 16 + lgrp * 4];
        acc[0][c] = bv; acc[1][c] = bv;
    }
    int r0 = rowbase + l16, r1 = rowbase + 16 + l16;
    bool v0 = r0 < N, v1 = r1 < N;
    size_t b0 = (size_t)(v0 ? r0 : 0) * K, b1 = (size_t)(v1 ? r1 : 0) * K;
    int nkk = K >> 5;
    for (int kk = 0; kk < nkk; ++kk) {
        int ko = kk * 32 + lgrp * 8;
        f32x4 lo0 = {0,0,0,0}, hi0 = {0,0,0,0}, lo1 = {0,0,0,0}, hi1 = {0,0,0,0};
        if (v0) { lo0 = *(const f32x4*)&X[b0 + ko]; hi0 = *(const f32x4*)&X[b0 + ko + 4]; }
        if (v1) { lo1 = *(const f32x4*)&X[b1 + ko]; hi1 = *(const f32x4*)&X[b1 + ko + 4]; }
        bf16x8 x0 = pack8(lo0, hi0);
        bf16x8 x1 = pack8(lo1, hi1);
#pragma unroll
        for (int c = 0; c < 8; ++c) {
            bf16x8 wa = *(const bf16x8*)&WT[(size_t)(c * 16 + l16) * K + ko];
            acc[0][c] = __builtin_amdgcn_mfma_f32_16x16x32_bf16(wa, x0, acc[0][c], 0, 0, 0);
            acc[1][c] = __builtin_amdgcn_mfma_f32_16x16x32_bf16(wa, x1, acc[1][c], 0, 0, 0);
        }
    }
    // epilogue: stage bf16 state tile to LDS only (row = tile-local node)
#pragma unroll
    for (int nt = 0; nt < 2; ++nt) {
        int lrow = w * 32 + nt * 16 + l16;
#pragma unroll
        for (int c = 0; c < 8; ++c) {
            int col = c * 16 + lgrp * 4;
            short4v s = pack4(acc[nt][c][0], acc[nt][c][1], acc[nt][c][2], acc[nt][c][3]);
            *(short4v*)&Xs[lrow * 136 + col] = s;
        }
    }
    __syncthreads();
    // contiguous xsb store: 16 threads x 16B cover one node's 256B row
#pragma unroll
    for (int j = 0; j < 8; ++j) {
        int flat = tid + j * 256;
        int row = flat >> 4, c8 = flat & 15;
        int node = n0 + row;
        if (node < N) {
            bf16x8 v = *(const bf16x8*)&Xs[row * 136 + c8 * 8];
            *(bf16x8*)((unsigned short*)xsb + ((size_t)t * N + node) * HD + c8 * 8) = v;
        }
    }
    qkv_phase(Xs, St, Wall, Ball, qo, kvo, t, n0, N, w, l16, lgrp);
}

// ------------- dst-centric gather: interleaved K|V records, width-32 shfl, 2-deep pipeline -------------
__global__ __launch_bounds__(256) void gather_kernel(
    const int* __restrict__ adj, const int* __restrict__ deg,
    const bf16* __restrict__ q, const bf16* __restrict__ kv,
    const float* __restrict__ prel, bf16* __restrict__ g, int N2, int N) {
    int grp = (blockIdx.x * 256 + threadIdx.x) >> 5;  // node in [0, 2N)
    int lane = threadIdx.x & 31;
    if (grp >= N2) return;
    int h = lane >> 3;

    ushort4 qa = *((const ushort4*)(q + (size_t)grp * HD) + lane);
    float q0 = bf2f(qa.x), q1 = bf2f(qa.y), q2 = bf2f(qa.z), q3 = bf2f(qa.w);
    const float is = 0.17677669529663687f; // 1/sqrt(32)
    float pr0 = prel[0 * H + h] * is, pr1 = prel[1 * H + h] * is, pr2 = prel[2 * H + h] * is;

    float m0 = 0.f, m1 = 0.f, m2 = 0.f, m3 = 0.f, dacc = 0.f;
    int dg = deg[grp]; if (dg > SLOTS) dg = SLOTS;
    const int* lst = adj + (size_t)grp * SLOTS;
    int myeA = (lane < dg) ? lst[lane] : 0;
    int myeB = (lane + 32 < dg) ? lst[lane + 32] : 0;

    if (dg > 0) {
        int ecur = __shfl(myeA, 0, 32);
        const bf16* base = kv + ((size_t)(ecur >> 20) * N + (ecur & 0xFFFFF)) * 256;
        ushort4 ka = *((const ushort4*)base + lane);
        ushort4 va = *((const ushort4*)base + 32 + lane);
        for (int i = 0; i < dg; ++i) {
            int en = 0;
            ushort4 kan = {0, 0, 0, 0}, van = {0, 0, 0, 0};
            if (i + 1 < dg) {  // prefetch next edge's record before processing current
                en = (i + 1 < 32) ? __shfl(myeA, i + 1, 32) : __shfl(myeB, i + 1 - 32, 32);
                const bf16* basen = kv + ((size_t)(en >> 20) * N + (en & 0xFFFFF)) * 256;
                kan = *((const ushort4*)basen + lane);
                van = *((const ushort4*)basen + 32 + lane);
            }
            int r = ecur >> 20;
            float p = q0 * bf2f(ka.x) + q1 * bf2f(ka.y) + q2 * bf2f(ka.z) + q3 * bf2f(ka.w);
            p = dpp8_sum(p);  // 8-lane head reduce at VALU speed
            float prv = (r == 0) ? pr0 : ((r == 1) ? pr1 : pr2);
            float eh = __expf(p * prv); // max-subtraction dropped: mathematically identical
            m0 = fmaf(eh, bf2f(va.x), m0);
            m1 = fmaf(eh, bf2f(va.y), m1);
            m2 = fmaf(eh, bf2f(va.z), m2);
            m3 = fmaf(eh, bf2f(va.w), m3);
            dacc += eh;
            ecur = en; ka = kan; va = van;
        }
    }
    float inv = dacc > 0.f ? 1.f / dacc : 0.f;
    const float c = 0.70710678118654752f;
    float v0 = m0 * inv, v1 = m1 * inv, v2 = m2 * inv, v3 = m3 * inv;
    float g0 = 0.5f * v0 * (1.f + erff(v0 * c));
    float g1 = 0.5f * v1 * (1.f + erff(v1 * c));
    float g2 = 0.5f * v2 * (1.f + erff(v2 * c));
    float g3 = 0.5f * v3 * (1.f + erff(v3 * c));
    *((short4v*)(g + (size_t)grp * HD) + lane) = pack4(g0, g1, g2, g3);
}

// ------------- fused: out GEMM (layer l, bf16 state) + qkv (layer l+1); t1 first -------------
// Blend writes go to S only; xsb then stored contiguously from S (the state tile is
// needed in S anyway for the next qkv_phase) — removes the last scattered global write.
__global__ __launch_bounds__(256) void out_qkv(
    bf16* __restrict__ xsb, const bf16* __restrict__ gbuf,
    const bf16* __restrict__ WoT, const float* __restrict__ bo,
    const float* __restrict__ skip,
    const bf16* __restrict__ Wall, const float* __restrict__ Ball,
    bf16* __restrict__ qo, bf16* __restrict__ kvo, int N, int nb0) {
    __shared__ short S[128 * 136];
    __shared__ short St[64 * 136];
    int b = blockIdx.x;
    int t = b < nb0 ? 1 : 0;
    int blk = t ? b : b - nb0;
    int tid = threadIdx.x;
    int w = tid >> 6, lane = tid & 63, l16 = lane & 15, lgrp = lane >> 4;
    int n0 = blk * 128;
    size_t NB = (size_t)N * HD;
    const bf16* G = gbuf + (size_t)t * NB;
#pragma unroll
    for (int j = 0; j < 8; ++j) {
        int flat = tid + j * 256;
        int row = flat >> 4, c16 = flat & 15;
        bf16x8 v = {0, 0, 0, 0, 0, 0, 0, 0};
        if (n0 + row < N) v = *(const bf16x8*)&G[(size_t)(n0 + row) * HD + c16 * 8];
        *(bf16x8*)&S[row * 136 + c16 * 8] = v;
    }
    __syncthreads();
    const bf16* WT = WoT + (size_t)t * 16384;
    bf16x8 Wc[2][4];
#pragma unroll
    for (int c2 = 0; c2 < 2; ++c2)
#pragma unroll
        for (int kk = 0; kk < 4; ++kk)
            Wc[c2][kk] = *(const bf16x8*)&WT[((w * 2 + c2) * 16 + l16) * 128 + kk * 32 + lgrp * 8];
    const float* bb = bo + t * 128;
    f32x4 bv0 = *(const f32x4*)&bb[(w * 2 + 0) * 16 + lgrp * 4];
    f32x4 bv1 = *(const f32x4*)&bb[(w * 2 + 1) * 16 + lgrp * 4];
    f32x4 acc[8][2];
#pragma unroll
    for (int rt = 0; rt < 8; ++rt) { acc[rt][0] = bv0; acc[rt][1] = bv1; }
#pragma unroll
    for (int rt = 0; rt < 8; ++rt) {
#pragma unroll
        for (int kk = 0; kk < 4; ++kk) {
            bf16x8 xb = *(const bf16x8*)&S[(rt * 16 + l16) * 136 + kk * 32 + lgrp * 8];
            acc[rt][0] = __builtin_amdgcn_mfma_f32_16x16x32_bf16(Wc[0][kk], xb, acc[rt][0], 0, 0, 0);
            acc[rt][1] = __builtin_amdgcn_mfma_f32_16x16x32_bf16(Wc[1][kk], xb, acc[rt][1], 0, 0, 0);
        }
    }
    float a = 1.f / (1.f + expf(-skip[t]));
    // batch all 16 independent xsb loads before the barrier (latency under barrier wait)
    short4v pv[8][2];
#pragma unroll
    for (int rt = 0; rt < 8; ++rt) {
        int node = n0 + rt * 16 + l16;
        size_t base = ((size_t)t * N + (size_t)(node < N ? node : 0)) * HD;
#pragma unroll
        for (int c2 = 0; c2 < 2; ++c2)
            pv[rt][c2] = *(const short4v*)((const unsigned short*)xsb + base + (w * 2 + c2) * 16 + lgrp * 4);
    }
    __syncthreads();  // all reads of S done; safe to overwrite with the new tile
#pragma unroll
    for (int rt = 0; rt < 8; ++rt) {
        int lrow = rt * 16 + l16;
        int node = n0 + lrow;
        bool vn = node < N;
#pragma unroll
        for (int c2 = 0; c2 < 2; ++c2) {
            int col = (w * 2 + c2) * 16 + lgrp * 4;
            short4v s;
            if (vn) {
                f32x4 o;
#pragma unroll
                for (int j = 0; j < 4; ++j)
                    o[j] = fmaxf(a * acc[rt][c2][j] + (1.f - a) * bf2f((unsigned short)pv[rt][c2][j]), 0.f);
                s = pack4(o[0], o[1], o[2], o[3]);
            } else {
                s = (short4v){0, 0, 0, 0};
            }
            *(short4v*)&S[lrow * 136 + col] = s;  // LDS only; xsb written contiguously below
        }
    }
    __syncthreads();
    // contiguous xsb store from S: 16 threads x 16B cover one node's 256B row
#pragma unroll
    for (int j = 0; j < 8; ++j) {
        int flat = tid + j * 256;
        int row = flat >> 4, c8 = flat & 15;
        int node = n0 + row;
        if (node < N) {
            bf16x8 v = *(const bf16x8*)&S[row * 136 + c8 * 8];
            *(bf16x8*)((unsigned short*)xsb + ((size_t)t * N + node) * HD + c8 * 8) = v;
        }
    }
    qkv_phase(S, St, Wall, Ball, qo, kvo, t, n0, N, w, l16, lgrp);
}

// ------------- final output: G tile in LDS; skip blend vs bf16 prev, ReLU, fp32 d_out -------------
// Output staged through Gs (free after MFMA) in two 64-node fp32 halves -> fully
// contiguous 16B/thread stores (4KB bursts).
__global__ __launch_bounds__(256) void out_gemm(
    float* __restrict__ xs, const bf16* __restrict__ xsb, const bf16* __restrict__ gbuf,
    const bf16* __restrict__ WoT, const float* __restrict__ bo,
    const float* __restrict__ skip, int N, int nb0) {
    __shared__ short Gs[128 * 136];
    float* Gf = (float*)Gs;  // fp32 staging view [64][132] = 33792 B <= 34816 B
    int b = blockIdx.x;
    int t = b >= nb0 ? 1 : 0;
    int blk = t ? b - nb0 : b;
    int tid = threadIdx.x;
    int w = tid >> 6, lane = tid & 63, l16 = lane & 15, lgrp = lane >> 4;
    int n0 = blk * 128;
    size_t NB = (size_t)N * HD;
    const bf16* G = gbuf + (size_t)t * NB;
#pragma unroll
    for (int j = 0; j < 8; ++j) {
        int flat = tid + j * 256;
        int row = flat >> 4, c16 = flat & 15;
        bf16x8 v = {0, 0, 0, 0, 0, 0, 0, 0};
        if (n0 + row < N) v = *(const bf16x8*)&G[(size_t)(n0 + row) * HD + c16 * 8];
        *(bf16x8*)&Gs[row * 136 + c16 * 8] = v;
    }
    __syncthreads();
    const bf16* WT = WoT + (size_t)t * 16384;
    bf16x8 Wc[2][4];
#pragma unroll
    for (int c2 = 0; c2 < 2; ++c2)
#pragma unroll
        for (int kk = 0; kk < 4; ++kk)
            Wc[c2][kk] = *(const bf16x8*)&WT[((w * 2 + c2) * 16 + l16) * 128 + kk * 32 + lgrp * 8];
    const float* bb = bo + t * 128;
    f32x4 bv0 = *(const f32x4*)&bb[(w * 2 + 0) * 16 + lgrp * 4];
    f32x4 bv1 = *(const f32x4*)&bb[(w * 2 + 1) * 16 + lgrp * 4];
    f32x4 acc[8][2];
#pragma unroll
    for (int rt = 0; rt < 8; ++rt) { acc[rt][0] = bv0; acc[rt][1] = bv1; }
#pragma unroll
    for (int rt = 0; rt < 8; ++rt) {
#pragma unroll
        for (int kk = 0; kk < 4; ++kk) {
            bf16x8 xb = *(const bf16x8*)&Gs[(rt * 16 + l16) * 136 + kk * 32 + lgrp * 8];
            acc[rt][0] = __builtin_amdgcn_mfma_f32_16x16x32_bf16(Wc[0][kk], xb, acc[rt][0], 0, 0, 0);
            acc[rt][1] = __builtin_amdgcn_mfma_f32_16x16x32_bf16(Wc[1][kk], xb, acc[rt][1], 0, 0, 0);
        }
    }
    float a = 1.f / (1.f + expf(-skip[t]));
    // batch the 16 independent xsb loads (blend inputs)
    short4v pv[8][2];
#pragma unroll
    for (int rt = 0; rt < 8; ++rt) {
        int node = n0 + rt * 16 + l16;
        size_t base = ((size_t)t * N + (size_t)(node < N ? node : 0)) * HD;
#pragma unroll
        for (int c2 = 0; c2 < 2; ++c2)
            pv[rt][c2] = *(const short4v*)((const unsigned short*)xsb + base + (w * 2 + c2) * 16 + lgrp * 4);
    }
    // staged fp32 output: two 64-node halves through Gf
#pragma unroll
    for (int half = 0; half < 2; ++half) {
        __syncthreads();  // Gs MFMA reads (half 0) / previous half's stores (half 1) done
#pragma unroll
        for (int q4 = 0; q4 < 4; ++q4) {
            int rt = half * 4 + q4;
#pragma unroll
            for (int c2 = 0; c2 < 2; ++c2) {
                f32x4 o;
#pragma unroll
                for (int j = 0; j < 4; ++j)
                    o[j] = fmaxf(a * acc[rt][c2][j] + (1.f - a) * bf2f((unsigned short)pv[rt][c2][j]), 0.f);
                *(f32x4*)&Gf[(q4 * 16 + l16) * 132 + (w * 2 + c2) * 16 + lgrp * 4] = o;
            }
        }
        __syncthreads();
        // 256 threads x 16B x 8 iters = 32 KB; 32 threads cover one node's 512B row
#pragma unroll
        for (int j = 0; j < 8; ++j) {
            int flat = tid + j * 256;
            int nl = flat >> 5, c16 = flat & 31;
            int node = n0 + half * 64 + nl;
            if (node < N) {
                f32x4 v = *(const f32x4*)&Gf[nl * 132 + c16 * 4];
                *(f32x4*)&xs[((size_t)t * N + node) * HD + c16 * 4] = v;
            }
        }
    }
}

extern "C" void kernel_launch(void* const* d_in, const int* in_sizes, int n_in,
                              void* d_out, int out_size, void* d_ws, size_t ws_size,
                              hipStream_t stream) {
    const float* x_region = (const float*)d_in[0];
    const float* x_site   = (const float*)d_in[1];
    const float* pWr  = (const float*)d_in[2];
    const float* pbr  = (const float*)d_in[3];
    const float* pWs  = (const float*)d_in[4];
    const float* pbs  = (const float*)d_in[5];
    const float* Wk   = (const float*)d_in[6];
    const float* bk   = (const float*)d_in[7];
    const float* Wq   = (const float*)d_in[8];
    const float* bq   = (const float*)d_in[9];
    const float* Wv   = (const float*)d_in[10];
    const float* bv   = (const float*)d_in[11];
    const float* Wo   = (const float*)d_in[12];
    const float* bo   = (const float*)d_in[13];
    const float* skip = (const float*)d_in[14];
    const float* Krel = (const float*)d_in[15];
    const float* Vrel = (const float*)d_in[16];
    const float* prel = (const float*)d_in[17];
    const int* e0 = (const int*)d_in[18];
    const int* e1 = (const int*)d_in[19];
    const int* e2 = (const int*)d_in[20];

    int N = in_sizes[0] / 64;   // 100000
    int E = in_sizes[18] / 2;   // 200000
    int nb0 = (N + 127) / 128;
    int N2 = 2 * N;

    float* xs = (float*)d_out;  // [2][N][128] fp32 — written once by the final out_gemm

    size_t NB = (size_t)N * HD;
    char* p = (char*)d_ws;
    bf16* q_bf  = (bf16*)p; p += 2 * NB * sizeof(bf16);          // [2][N][128]
    bf16* kv_bf = (bf16*)p; p += 3 * (size_t)N * 256 * sizeof(bf16); // [3][N][K(128)|V(128)]
    bf16* g_bf  = (bf16*)p; p += 2 * NB * sizeof(bf16);
    bf16* xsb   = (bf16*)p; p += 2 * NB * sizeof(bf16);          // bf16 node state (intermediate xs)
    int*  adj   = (int*)p;  p += (size_t)N2 * SLOTS * sizeof(int);
    int*  deg   = (int*)p;  p += (size_t)N2 * sizeof(int);
    bf16* PWrT  = (bf16*)p; p += 8192 * sizeof(bf16);            // [128][64]
    bf16* PWsT  = (bf16*)p; p += 4096 * sizeof(bf16);            // [128][32]
    bf16* Wall  = (bf16*)p; p += 2 * 8 * 16384 * sizeof(bf16);   // [L][8][128][128]
    bf16* WoT_a = (bf16*)p; p += 2 * 2 * 16384 * sizeof(bf16);   // [L][2][128][128]
    float* Ball = (float*)p; p += 2 * 8 * 128 * sizeof(float);   // [L][8][128]
    (void)ws_size; (void)n_in; (void)out_size;

    // ---- adjacency (edge lists are launch-constant) ----
    hipMemsetAsync(deg, 0, (size_t)N2 * sizeof(int), stream);
    int bgrid = (E + 255) / 256;
    build_adj<<<bgrid, 256, 0, stream>>>(e0, adj, deg, N, 0, E); // r2s -> dst type 1
    build_adj<<<bgrid, 256, 0, stream>>>(e1, adj, deg, 0, 1, E); // s2r -> dst type 0
    build_adj<<<bgrid, 256, 0, stream>>>(e2, adj, deg, N, 2, E); // s2s -> dst type 1

    // ---- weight prep ----
    transpose_bf16<<<32, 256, 0, stream>>>(pWr, PWrT, 64, 128, 64, 8192);
    transpose_bf16<<<16, 256, 0, stream>>>(pWs, PWsT, 32, 128, 32, 4096);
    for (int l = 0; l < 2; ++l) {
        transpose_bf16<<<128, 256, 0, stream>>>(Wq + (size_t)l * 2 * 16384,
                                                Wall + (size_t)l * 8 * 16384, 128, 128, 128, 32768);
        transpose_bf16<<<128, 256, 0, stream>>>(Wo + (size_t)l * 2 * 16384,
                                                WoT_a + (size_t)l * 2 * 16384, 128, 128, 128, 32768);
    }
    fuse_relw<<<768, 256, 0, stream>>>(Wk, Wv, Krel, Vrel, Wall);
    fuse_relb<<<8, 256, 0, stream>>>(bk, bv, bq, Krel, Vrel, Ball);

    int ggrid = (N2 * 32 + 255) / 256;

    // layer 0: fused proj + qkv (bf16 node state)
    proj_qkv<<<2 * nb0, 256, 0, stream>>>(
        x_region, x_site, PWrT, pbr, PWsT, pbs, xsb,
        Wall, Ball, q_bf, kv_bf, N, nb0);
    gather_kernel<<<ggrid, 256, 0, stream>>>(
        adj, deg, q_bf, kv_bf, prel, g_bf, N2, N);
    // layer seam: fused out(l0) + qkv(l1), bf16 state round-trip only
    out_qkv<<<2 * nb0, 256, 0, stream>>>(
        xsb, g_bf, WoT_a, bo, skip,
        Wall + (size_t)8 * 16384, Ball + 8 * 128, q_bf, kv_bf, N, nb0);
    gather_kernel<<<ggrid, 256, 0, stream>>>(
        adj, deg, q_bf, kv_bf, prel + 12, g_bf, N2, N);
    // final out (l1): blend vs bf16 prev, write fp32 d_out
    out_gemm<<<2 * nb0, 256, 0, stream>>>(
        xs, xsb, g_bf, WoT_a + (size_t)2 * 16384, bo + 2 * HD, skip + 2, N, nb0);
}

// Round 12
// 473.939 us; speedup vs baseline: 1.2833x; 1.0030x over previous
//
#include <hip/hip_runtime.h>
#include <hip/hip_bf16.h>

#define HD 128
#define H 4
#define D 32
#define SLOTS 64

typedef __hip_bfloat16 bf16;
typedef __attribute__((ext_vector_type(8))) short bf16x8;
typedef __attribute__((ext_vector_type(4))) float f32x4;
typedef __attribute__((ext_vector_type(4))) short short4v;

__device__ __forceinline__ float bf2f(unsigned short u) {
    union { unsigned int i; float f; } v; v.i = ((unsigned int)u) << 16; return v.f;
}
__device__ __forceinline__ short f2bf(float f) {
    union { float f; unsigned u; } v; v.f = f;
    unsigned r = v.u + 0x7fff + ((v.u >> 16) & 1);
    return (short)(r >> 16);
}
// HW packed fp32->bf16 (RNE), 2 values/instr
__device__ __forceinline__ short4v pack4(float a0, float a1, float a2, float a3) {
    union { unsigned u[2]; short4v v; } r;
    asm("v_cvt_pk_bf16_f32 %0, %1, %2" : "=v"(r.u[0]) : "v"(a0), "v"(a1));
    asm("v_cvt_pk_bf16_f32 %0, %1, %2" : "=v"(r.u[1]) : "v"(a2), "v"(a3));
    return r.v;
}
__device__ __forceinline__ bf16x8 pack8(const f32x4 lo, const f32x4 hi) {
    union { unsigned u[4]; bf16x8 v; } r;
    asm("v_cvt_pk_bf16_f32 %0, %1, %2" : "=v"(r.u[0]) : "v"(lo[0]), "v"(lo[1]));
    asm("v_cvt_pk_bf16_f32 %0, %1, %2" : "=v"(r.u[1]) : "v"(lo[2]), "v"(lo[3]));
    asm("v_cvt_pk_bf16_f32 %0, %1, %2" : "=v"(r.u[2]) : "v"(hi[0]), "v"(hi[1]));
    asm("v_cvt_pk_bf16_f32 %0, %1, %2" : "=v"(r.u[3]) : "v"(hi[2]), "v"(hi[3]));
    return r.v;
}
// 8-lane-group sum at VALU speed via DPP (quad_perm xor1, xor2, row_half_mirror).
__device__ __forceinline__ float dpp8_sum(float p) {
    union { int i; float f; } u, v;
    u.f = p;
    v.i = __builtin_amdgcn_mov_dpp(u.i, 0xB1, 0xF, 0xF, true);  p += v.f; u.f = p;  // quad_perm xor1
    v.i = __builtin_amdgcn_mov_dpp(u.i, 0x4E, 0xF, 0xF, true);  p += v.f; u.f = p;  // quad_perm xor2
    v.i = __builtin_amdgcn_mov_dpp(u.i, 0x141, 0xF, 0xF, true); p += v.f;           // row_half_mirror
    return p;
}

// ---------------- weight pre-transpose: dst[b][c][kd] = bf16(src[b][k][c]) ----------------
__global__ __launch_bounds__(256) void transpose_bf16(
    const float* __restrict__ src, bf16* __restrict__ dst, int K, int C, int Kd, int total) {
    int i = blockIdx.x * 256 + threadIdx.x;
    if (i >= total) return;
    int kd = i % Kd; int rem = i / Kd; int c = rem % C; int b = rem / C;
    float v = (kd < K) ? src[((size_t)b * K + kd) * C + c] : 0.f;
    ((unsigned short*)dst)[i] = (unsigned short)f2bf(v);
}

// ---------------- fuse relation transforms into k/v weights ----------------
__global__ __launch_bounds__(256) void fuse_relw(
    const float* __restrict__ Wk, const float* __restrict__ Wv,
    const float* __restrict__ Krel, const float* __restrict__ Vrel,
    bf16* __restrict__ Wall) {
    int gid = blockIdx.x * 256 + threadIdx.x;  // 12 * 16384
    int m = gid >> 14;
    int idx = gid & 16383;
    int ep = idx >> 7, i = idx & 127;
    int l = m / 6, kv = (m / 3) & 1, r = m % 3;
    int s = (r == 0) ? 0 : 1;
    const float* W = (kv ? Wv : Wk) + ((size_t)(l * 2 + s)) * 16384;
    const float* R = (kv ? Vrel : Krel) + ((size_t)(l * 3 + r)) * 4096;
    int h = ep >> 5, e = ep & 31;
    float acc = 0.f;
#pragma unroll
    for (int d = 0; d < 32; ++d)
        acc = fmaf(W[i * 128 + h * 32 + d], R[h * 1024 + d * 32 + e], acc);
    int slot = l * 8 + 2 + kv * 3 + r;
    ((unsigned short*)Wall)[(size_t)slot * 16384 + ep * 128 + i] = (unsigned short)f2bf(acc);
}

// Ball layout per layer: [8][128] fp32; slots 0,1 = bq; 2..4 fused bk; 5..7 fused bv
__global__ __launch_bounds__(256) void fuse_relb(
    const float* __restrict__ bk, const float* __restrict__ bv, const float* __restrict__ bq,
    const float* __restrict__ Krel, const float* __restrict__ Vrel,
    float* __restrict__ Ball) {
    int gid = blockIdx.x * 256 + threadIdx.x;  // 2048
    if (gid >= 2048) return;
    int col = gid & 127, m = gid >> 7;
    int l = m >> 3, g = m & 7;
    float val;
    if (g < 2) {
        val = bq[(l * 2 + g) * 128 + col];
    } else {
        int kv = (g - 2) / 3, r = (g - 2) % 3, s = (r == 0) ? 0 : 1;
        const float* b = (kv ? bv : bk) + (size_t)(l * 2 + s) * 128;
        const float* R = (kv ? Vrel : Krel) + (size_t)(l * 3 + r) * 4096;
        int h = col >> 5, e = col & 31;
        float acc = 0.f;
#pragma unroll
        for (int d = 0; d < 32; ++d)
            acc = fmaf(b[h * 32 + d], R[h * 1024 + d * 32 + e], acc);
        val = acc;
    }
    Ball[gid] = val;
}

// ---------------- adjacency build: fixed 64 slots per dst node ----------------
__global__ __launch_bounds__(256) void build_adj(
    const int* __restrict__ edge, int* __restrict__ adj, int* __restrict__ deg,
    int dstBase, int rel, int E) {
    int i = blockIdx.x * 256 + threadIdx.x;
    if (i >= E) return;
    int src = edge[i];
    int dst = edge[E + i];
    int slot = atomicAdd(deg + dstBase + dst, 1);
    if (slot < SLOTS) adj[(size_t)(dstBase + dst) * SLOTS + slot] = src | (rel << 20);
}

// ---------------- shared qkv slice phase with LDS store-staging ----------------
// Compute as before (acc[8][2] per wave), but bounce output through St[64][136] in two
// 64-node halves so global stores are 16B/thread, 256B-contiguous per node row (full 64B
// lines; q rows coalesce into 4KB bursts). r9: this lifted out_qkv 151->120us.
__device__ __forceinline__ void qkv_phase(
    const short* Xs, short* St, const bf16* __restrict__ Wall, const float* __restrict__ Ball,
    bf16* __restrict__ qo, bf16* __restrict__ kvo,
    int t, int n0, int N, int w, int l16, int lgrp) {
    size_t NB = (size_t)N * HD;
    int tid = threadIdx.x;
    int nsl = t ? 5 : 3;
    unsigned list = t ? 0x76431u : 0x520u;  // slice ids, 4 bits each
    for (int si = 0; si < nsl; ++si) {
        int g = (list >> (4 * si)) & 15;
        const bf16* WT = Wall + (size_t)g * 16384;
        bf16x8 Wc[2][4];
#pragma unroll
        for (int c2 = 0; c2 < 2; ++c2)
#pragma unroll
            for (int kk = 0; kk < 4; ++kk)
                Wc[c2][kk] = *(const bf16x8*)&WT[((w * 2 + c2) * 16 + l16) * 128 + kk * 32 + lgrp * 8];
        const float* bb = Ball + g * 128;
        f32x4 bv0 = *(const f32x4*)&bb[(w * 2 + 0) * 16 + lgrp * 4];
        f32x4 bv1 = *(const f32x4*)&bb[(w * 2 + 1) * 16 + lgrp * 4];
        f32x4 acc[8][2];
#pragma unroll
        for (int rt = 0; rt < 8; ++rt) { acc[rt][0] = bv0; acc[rt][1] = bv1; }
#pragma unroll
        for (int rt = 0; rt < 8; ++rt) {
#pragma unroll
            for (int kk = 0; kk < 4; ++kk) {
                bf16x8 xb = *(const bf16x8*)&Xs[(rt * 16 + l16) * 136 + kk * 32 + lgrp * 8];
                acc[rt][0] = __builtin_amdgcn_mfma_f32_16x16x32_bf16(Wc[0][kk], xb, acc[rt][0], 0, 0, 0);
                acc[rt][1] = __builtin_amdgcn_mfma_f32_16x16x32_bf16(Wc[1][kk], xb, acc[rt][1], 0, 0, 0);
            }
        }
        // dest: q -> [g][node][128]; K/V -> interleaved [r][node][K|V] 256-elem records
        unsigned short* outp;
        int rowStride, off2;
        if (g < 2) {
            outp = (unsigned short*)(qo + (size_t)g * NB);
            rowStride = HD; off2 = 0;
        } else {
            int gi = g - 2, r = gi % 3, isV = gi / 3;
            outp = (unsigned short*)(kvo + (size_t)r * N * 256);
            rowStride = 256; off2 = isV * 128;
        }
        // staged store: two 64-node halves through St
#pragma unroll
        for (int half = 0; half < 2; ++half) {
            __syncthreads();  // St free (previous half's / slice's reads done)
#pragma unroll
            for (int q4 = 0; q4 < 4; ++q4) {
                int rt = half * 4 + q4;
#pragma unroll
                for (int c2 = 0; c2 < 2; ++c2) {
                    short4v s = pack4(acc[rt][c2][0], acc[rt][c2][1], acc[rt][c2][2], acc[rt][c2][3]);
                    *(short4v*)&St[(q4 * 16 + l16) * 136 + (w * 2 + c2) * 16 + lgrp * 4] = s;
                }
            }
            __syncthreads();
            // 256 threads x 16B x 4 iters = 16 KB; 16 threads cover one node's 256B row
#pragma unroll
            for (int j = 0; j < 4; ++j) {
                int flat = tid + j * 256;
                int nl = flat >> 4, c8 = flat & 15;
                int node = n0 + half * 64 + nl;
                if (node < N) {
                    bf16x8 v = *(const bf16x8*)&St[nl * 136 + c8 * 8];
                    *(bf16x8*)(outp + (size_t)node * rowStride + off2 + c8 * 8) = v;
                }
            }
        }
    }
}

// ---------------- fused: initial projection (bf16 state out) + layer-0 qkv ----------------
__global__ __launch_bounds__(256) void proj_qkv(
    const float* __restrict__ xr, const float* __restrict__ xsi,
    const bf16* __restrict__ WrT, const float* __restrict__ br,
    const bf16* __restrict__ WsT, const float* __restrict__ bs,
    bf16* __restrict__ xsb,
    const bf16* __restrict__ Wall, const float* __restrict__ Ball,
    bf16* __restrict__ qo, bf16* __restrict__ kvo, int N, int nb0) {
    __shared__ short Xs[128 * 136];
    __shared__ short St[64 * 136];
    int b = blockIdx.x;
    int t = b < nb0 ? 1 : 0;
    int blk = t ? b : b - nb0;
    int tid = threadIdx.x;
    int w = tid >> 6, lane = tid & 63, l16 = lane & 15, lgrp = lane >> 4;
    int n0 = blk * 128;
    int rowbase = n0 + w * 32;
    int K = t ? 32 : 64;
    const float* X = t ? xsi : xr;
    const bf16* WT = t ? WsT : WrT;  // [128][K]
    const float* bb = t ? bs : br;
    f32x4 acc[2][8];
#pragma unroll
    for (int c = 0; c < 8; ++c) {
        f32x4 bv = *(const f32x4*)&bb[c * 16 + lgrp * 4];
        acc[0][c] = bv; acc[1][c] = bv;
    }
    int r0 = rowbase + l16, r1 = rowbase + 16 + l16;
    bool v0 = r0 < N, v1 = r1 < N;
    size_t b0 = (size_t)(v0 ? r0 : 0) * K, b1 = (size_t)(v1 ? r1 : 0) * K;
    int nkk = K >> 5;
    for (int kk = 0; kk < nkk; ++kk) {
        int ko = kk * 32 + lgrp * 8;
        f32x4 lo0 = {0,0,0,0}, hi0 = {0,0,0,0}, lo1 = {0,0,0,0}, hi1 = {0,0,0,0};
        if (v0) { lo0 = *(const f32x4*)&X[b0 + ko]; hi0 = *(const f32x4*)&X[b0 + ko + 4]; }
        if (v1) { lo1 = *(const f32x4*)&X[b1 + ko]; hi1 = *(const f32x4*)&X[b1 + ko + 4]; }
        bf16x8 x0 = pack8(lo0, hi0);
        bf16x8 x1 = pack8(lo1, hi1);
#pragma unroll
        for (int c = 0; c < 8; ++c) {
            bf16x8 wa = *(const bf16x8*)&WT[(size_t)(c * 16 + l16) * K + ko];
            acc[0][c] = __builtin_amdgcn_mfma_f32_16x16x32_bf16(wa, x0, acc[0][c], 0, 0, 0);
            acc[1][c] = __builtin_amdgcn_mfma_f32_16x16x32_bf16(wa, x1, acc[1][c], 0, 0, 0);
        }
    }
    // epilogue: stage bf16 state tile to LDS only (row = tile-local node)
#pragma unroll
    for (int nt = 0; nt < 2; ++nt) {
        int lrow = w * 32 + nt * 16 + l16;
#pragma unroll
        for (int c = 0; c < 8; ++c) {
            int col = c * 16 + lgrp * 4;
            short4v s = pack4(acc[nt][c][0], acc[nt][c][1], acc[nt][c][2], acc[nt][c][3]);
            *(short4v*)&Xs[lrow * 136 + col] = s;
        }
    }
    __syncthreads();
    // contiguous xsb store: 16 threads x 16B cover one node's 256B row
#pragma unroll
    for (int j = 0; j < 8; ++j) {
        int flat = tid + j * 256;
        int row = flat >> 4, c8 = flat & 15;
        int node = n0 + row;
        if (node < N) {
            bf16x8 v = *(const bf16x8*)&Xs[row * 136 + c8 * 8];
            *(bf16x8*)((unsigned short*)xsb + ((size_t)t * N + node) * HD + c8 * 8) = v;
        }
    }
    qkv_phase(Xs, St, Wall, Ball, qo, kvo, t, n0, N, w, l16, lgrp);
}

// ------------- dst-centric gather: interleaved K|V records, width-32 shfl, 2-deep pipeline -------------
__global__ __launch_bounds__(256) void gather_kernel(
    const int* __restrict__ adj, const int* __restrict__ deg,
    const bf16* __restrict__ q, const bf16* __restrict__ kv,
    const float* __restrict__ prel, bf16* __restrict__ g, int N2, int N) {
    int grp = (blockIdx.x * 256 + threadIdx.x) >> 5;  // node in [0, 2N)
    int lane = threadIdx.x & 31;
    if (grp >= N2) return;
    int h = lane >> 3;

    ushort4 qa = *((const ushort4*)(q + (size_t)grp * HD) + lane);
    float q0 = bf2f(qa.x), q1 = bf2f(qa.y), q2 = bf2f(qa.z), q3 = bf2f(qa.w);
    const float is = 0.17677669529663687f; // 1/sqrt(32)
    float pr0 = prel[0 * H + h] * is, pr1 = prel[1 * H + h] * is, pr2 = prel[2 * H + h] * is;

    float m0 = 0.f, m1 = 0.f, m2 = 0.f, m3 = 0.f, dacc = 0.f;
    int dg = deg[grp]; if (dg > SLOTS) dg = SLOTS;
    const int* lst = adj + (size_t)grp * SLOTS;
    int myeA = (lane < dg) ? lst[lane] : 0;
    int myeB = (lane + 32 < dg) ? lst[lane + 32] : 0;

    if (dg > 0) {
        int ecur = __shfl(myeA, 0, 32);
        const bf16* base = kv + ((size_t)(ecur >> 20) * N + (ecur & 0xFFFFF)) * 256;
        ushort4 ka = *((const ushort4*)base + lane);
        ushort4 va = *((const ushort4*)base + 32 + lane);
        for (int i = 0; i < dg; ++i) {
            int en = 0;
            ushort4 kan = {0, 0, 0, 0}, van = {0, 0, 0, 0};
            if (i + 1 < dg) {  // prefetch next edge's record before processing current
                en = (i + 1 < 32) ? __shfl(myeA, i + 1, 32) : __shfl(myeB, i + 1 - 32, 32);
                const bf16* basen = kv + ((size_t)(en >> 20) * N + (en & 0xFFFFF)) * 256;
                kan = *((const ushort4*)basen + lane);
                van = *((const ushort4*)basen + 32 + lane);
            }
            int r = ecur >> 20;
            float p = q0 * bf2f(ka.x) + q1 * bf2f(ka.y) + q2 * bf2f(ka.z) + q3 * bf2f(ka.w);
            p = dpp8_sum(p);  // 8-lane head reduce at VALU speed
            float prv = (r == 0) ? pr0 : ((r == 1) ? pr1 : pr2);
            float eh = __expf(p * prv); // max-subtraction dropped: mathematically identical
            m0 = fmaf(eh, bf2f(va.x), m0);
            m1 = fmaf(eh, bf2f(va.y), m1);
            m2 = fmaf(eh, bf2f(va.z), m2);
            m3 = fmaf(eh, bf2f(va.w), m3);
            dacc += eh;
            ecur = en; ka = kan; va = van;
        }
    }
    float inv = dacc > 0.f ? 1.f / dacc : 0.f;
    const float c = 0.70710678118654752f;
    float v0 = m0 * inv, v1 = m1 * inv, v2 = m2 * inv, v3 = m3 * inv;
    float g0 = 0.5f * v0 * (1.f + erff(v0 * c));
    float g1 = 0.5f * v1 * (1.f + erff(v1 * c));
    float g2 = 0.5f * v2 * (1.f + erff(v2 * c));
    float g3 = 0.5f * v3 * (1.f + erff(v3 * c));
    *((short4v*)(g + (size_t)grp * HD) + lane) = pack4(g0, g1, g2, g3);
}

// ------------- fused: out GEMM (layer l, bf16 state) + qkv (layer l+1); t1 first -------------
// Blend writes go to S only; xsb then stored contiguously from S (the state tile is
// needed in S anyway for the next qkv_phase).
__global__ __launch_bounds__(256) void out_qkv(
    bf16* __restrict__ xsb, const bf16* __restrict__ gbuf,
    const bf16* __restrict__ WoT, const float* __restrict__ bo,
    const float* __restrict__ skip,
    const bf16* __restrict__ Wall, const float* __restrict__ Ball,
    bf16* __restrict__ qo, bf16* __restrict__ kvo, int N, int nb0) {
    __shared__ short S[128 * 136];
    __shared__ short St[64 * 136];
    int b = blockIdx.x;
    int t = b < nb0 ? 1 : 0;
    int blk = t ? b : b - nb0;
    int tid = threadIdx.x;
    int w = tid >> 6, lane = tid & 63, l16 = lane & 15, lgrp = lane >> 4;
    int n0 = blk * 128;
    size_t NB = (size_t)N * HD;
    const bf16* G = gbuf + (size_t)t * NB;
#pragma unroll
    for (int j = 0; j < 8; ++j) {
        int flat = tid + j * 256;
        int row = flat >> 4, c16 = flat & 15;
        bf16x8 v = {0, 0, 0, 0, 0, 0, 0, 0};
        if (n0 + row < N) v = *(const bf16x8*)&G[(size_t)(n0 + row) * HD + c16 * 8];
        *(bf16x8*)&S[row * 136 + c16 * 8] = v;
    }
    __syncthreads();
    const bf16* WT = WoT + (size_t)t * 16384;
    bf16x8 Wc[2][4];
#pragma unroll
    for (int c2 = 0; c2 < 2; ++c2)
#pragma unroll
        for (int kk = 0; kk < 4; ++kk)
            Wc[c2][kk] = *(const bf16x8*)&WT[((w * 2 + c2) * 16 + l16) * 128 + kk * 32 + lgrp * 8];
    const float* bb = bo + t * 128;
    f32x4 bv0 = *(const f32x4*)&bb[(w * 2 + 0) * 16 + lgrp * 4];
    f32x4 bv1 = *(const f32x4*)&bb[(w * 2 + 1) * 16 + lgrp * 4];
    f32x4 acc[8][2];
#pragma unroll
    for (int rt = 0; rt < 8; ++rt) { acc[rt][0] = bv0; acc[rt][1] = bv1; }
#pragma unroll
    for (int rt = 0; rt < 8; ++rt) {
#pragma unroll
        for (int kk = 0; kk < 4; ++kk) {
            bf16x8 xb = *(const bf16x8*)&S[(rt * 16 + l16) * 136 + kk * 32 + lgrp * 8];
            acc[rt][0] = __builtin_amdgcn_mfma_f32_16x16x32_bf16(Wc[0][kk], xb, acc[rt][0], 0, 0, 0);
            acc[rt][1] = __builtin_amdgcn_mfma_f32_16x16x32_bf16(Wc[1][kk], xb, acc[rt][1], 0, 0, 0);
        }
    }
    float a = 1.f / (1.f + expf(-skip[t]));
    // batch all 16 independent xsb loads before the barrier (latency under barrier wait)
    short4v pv[8][2];
#pragma unroll
    for (int rt = 0; rt < 8; ++rt) {
        int node = n0 + rt * 16 + l16;
        size_t base = ((size_t)t * N + (size_t)(node < N ? node : 0)) * HD;
#pragma unroll
        for (int c2 = 0; c2 < 2; ++c2)
            pv[rt][c2] = *(const short4v*)((const unsigned short*)xsb + base + (w * 2 + c2) * 16 + lgrp * 4);
    }
    __syncthreads();  // all reads of S done; safe to overwrite with the new tile
#pragma unroll
    for (int rt = 0; rt < 8; ++rt) {
        int lrow = rt * 16 + l16;
        int node = n0 + lrow;
        bool vn = node < N;
#pragma unroll
        for (int c2 = 0; c2 < 2; ++c2) {
            int col = (w * 2 + c2) * 16 + lgrp * 4;
            short4v s;
            if (vn) {
                f32x4 o;
#pragma unroll
                for (int j = 0; j < 4; ++j)
                    o[j] = fmaxf(a * acc[rt][c2][j] + (1.f - a) * bf2f((unsigned short)pv[rt][c2][j]), 0.f);
                s = pack4(o[0], o[1], o[2], o[3]);
            } else {
                s = (short4v){0, 0, 0, 0};
            }
            *(short4v*)&S[lrow * 136 + col] = s;  // LDS only; xsb written contiguously below
        }
    }
    __syncthreads();
    // contiguous xsb store from S: 16 threads x 16B cover one node's 256B row
#pragma unroll
    for (int j = 0; j < 8; ++j) {
        int flat = tid + j * 256;
        int row = flat >> 4, c8 = flat & 15;
        int node = n0 + row;
        if (node < N) {
            bf16x8 v = *(const bf16x8*)&S[row * 136 + c8 * 8];
            *(bf16x8*)((unsigned short*)xsb + ((size_t)t * N + node) * HD + c8 * 8) = v;
        }
    }
    qkv_phase(S, St, Wall, Ball, qo, kvo, t, n0, N, w, l16, lgrp);
}

// ------------- final output: G tile in LDS; skip blend vs bf16 prev, ReLU, fp32 d_out -------------
// Output staged through Gs (free after MFMA) in two 64-node fp32 halves -> fully
// contiguous 16B/thread stores (4KB bursts).
__global__ __launch_bounds__(256) void out_gemm(
    float* __restrict__ xs, const bf16* __restrict__ xsb, const bf16* __restrict__ gbuf,
    const bf16* __restrict__ WoT, const float* __restrict__ bo,
    const float* __restrict__ skip, int N, int nb0) {
    __shared__ short Gs[128 * 136];
    float* Gf = (float*)Gs;  // fp32 staging view [64][132] = 33792 B <= 34816 B
    int b = blockIdx.x;
    int t = b >= nb0 ? 1 : 0;
    int blk = t ? b - nb0 : b;
    int tid = threadIdx.x;
    int w = tid >> 6, lane = tid & 63, l16 = lane & 15, lgrp = lane >> 4;
    int n0 = blk * 128;
    size_t NB = (size_t)N * HD;
    const bf16* G = gbuf + (size_t)t * NB;
#pragma unroll
    for (int j = 0; j < 8; ++j) {
        int flat = tid + j * 256;
        int row = flat >> 4, c16 = flat & 15;
        bf16x8 v = {0, 0, 0, 0, 0, 0, 0, 0};
        if (n0 + row < N) v = *(const bf16x8*)&G[(size_t)(n0 + row) * HD + c16 * 8];
        *(bf16x8*)&Gs[row * 136 + c16 * 8] = v;
    }
    __syncthreads();
    const bf16* WT = WoT + (size_t)t * 16384;
    bf16x8 Wc[2][4];
#pragma unroll
    for (int c2 = 0; c2 < 2; ++c2)
#pragma unroll
        for (int kk = 0; kk < 4; ++kk)
            Wc[c2][kk] = *(const bf16x8*)&WT[((w * 2 + c2) * 16 + l16) * 128 + kk * 32 + lgrp * 8];
    const float* bb = bo + t * 128;
    f32x4 bv0 = *(const f32x4*)&bb[(w * 2 + 0) * 16 + lgrp * 4];
    f32x4 bv1 = *(const f32x4*)&bb[(w * 2 + 1) * 16 + lgrp * 4];
    f32x4 acc[8][2];
#pragma unroll
    for (int rt = 0; rt < 8; ++rt) { acc[rt][0] = bv0; acc[rt][1] = bv1; }
#pragma unroll
    for (int rt = 0; rt < 8; ++rt) {
#pragma unroll
        for (int kk = 0; kk < 4; ++kk) {
            bf16x8 xb = *(const bf16x8*)&Gs[(rt * 16 + l16) * 136 + kk * 32 + lgrp * 8];
            acc[rt][0] = __builtin_amdgcn_mfma_f32_16x16x32_bf16(Wc[0][kk], xb, acc[rt][0], 0, 0, 0);
            acc[rt][1] = __builtin_amdgcn_mfma_f32_16x16x32_bf16(Wc[1][kk], xb, acc[rt][1], 0, 0, 0);
        }
    }
    float a = 1.f / (1.f + expf(-skip[t]));
    // batch the 16 independent xsb loads (blend inputs)
    short4v pv[8][2];
#pragma unroll
    for (int rt = 0; rt < 8; ++rt) {
        int node = n0 + rt * 16 + l16;
        size_t base = ((size_t)t * N + (size_t)(node < N ? node : 0)) * HD;
#pragma unroll
        for (int c2 = 0; c2 < 2; ++c2)
            pv[rt][c2] = *(const short4v*)((const unsigned short*)xsb + base + (w * 2 + c2) * 16 + lgrp * 4);
    }
    // staged fp32 output: two 64-node halves through Gf
#pragma unroll
    for (int half = 0; half < 2; ++half) {
        __syncthreads();  // Gs MFMA reads (half 0) / previous half's stores (half 1) done
#pragma unroll
        for (int q4 = 0; q4 < 4; ++q4) {
            int rt = half * 4 + q4;
#pragma unroll
            for (int c2 = 0; c2 < 2; ++c2) {
                f32x4 o;
#pragma unroll
                for (int j = 0; j < 4; ++j)
                    o[j] = fmaxf(a * acc[rt][c2][j] + (1.f - a) * bf2f((unsigned short)pv[rt][c2][j]), 0.f);
                *(f32x4*)&Gf[(q4 * 16 + l16) * 132 + (w * 2 + c2) * 16 + lgrp * 4] = o;
            }
        }
        __syncthreads();
        // 256 threads x 16B x 8 iters = 32 KB; 32 threads cover one node's 512B row
#pragma unroll
        for (int j = 0; j < 8; ++j) {
            int flat = tid + j * 256;
            int nl = flat >> 5, c16 = flat & 31;
            int node = n0 + half * 64 + nl;
            if (node < N) {
                f32x4 v = *(const f32x4*)&Gf[nl * 132 + c16 * 4];
                *(f32x4*)&xs[((size_t)t * N + node) * HD + c16 * 4] = v;
            }
        }
    }
}

extern "C" void kernel_launch(void* const* d_in, const int* in_sizes, int n_in,
                              void* d_out, int out_size, void* d_ws, size_t ws_size,
                              hipStream_t stream) {
    const float* x_region = (const float*)d_in[0];
    const float* x_site   = (const float*)d_in[1];
    const float* pWr  = (const float*)d_in[2];
    const float* pbr  = (const float*)d_in[3];
    const float* pWs  = (const float*)d_in[4];
    const float* pbs  = (const float*)d_in[5];
    const float* Wk   = (const float*)d_in[6];
    const float* bk   = (const float*)d_in[7];
    const float* Wq   = (const float*)d_in[8];
    const float* bq   = (const float*)d_in[9];
    const float* Wv   = (const float*)d_in[10];
    const float* bv   = (const float*)d_in[11];
    const float* Wo   = (const float*)d_in[12];
    const float* bo   = (const float*)d_in[13];
    const float* skip = (const float*)d_in[14];
    const float* Krel = (const float*)d_in[15];
    const float* Vrel = (const float*)d_in[16];
    const float* prel = (const float*)d_in[17];
    const int* e0 = (const int*)d_in[18];
    const int* e1 = (const int*)d_in[19];
    const int* e2 = (const int*)d_in[20];

    int N = in_sizes[0] / 64;   // 100000
    int E = in_sizes[18] / 2;   // 200000
    int nb0 = (N + 127) / 128;
    int N2 = 2 * N;

    float* xs = (float*)d_out;  // [2][N][128] fp32 — written once by the final out_gemm

    size_t NB = (size_t)N * HD;
    char* p = (char*)d_ws;
    bf16* q_bf  = (bf16*)p; p += 2 * NB * sizeof(bf16);          // [2][N][128]
    bf16* kv_bf = (bf16*)p; p += 3 * (size_t)N * 256 * sizeof(bf16); // [3][N][K(128)|V(128)]
    bf16* g_bf  = (bf16*)p; p += 2 * NB * sizeof(bf16);
    bf16* xsb   = (bf16*)p; p += 2 * NB * sizeof(bf16);          // bf16 node state (intermediate xs)
    int*  adj   = (int*)p;  p += (size_t)N2 * SLOTS * sizeof(int);
    int*  deg   = (int*)p;  p += (size_t)N2 * sizeof(int);
    bf16* PWrT  = (bf16*)p; p += 8192 * sizeof(bf16);            // [128][64]
    bf16* PWsT  = (bf16*)p; p += 4096 * sizeof(bf16);            // [128][32]
    bf16* Wall  = (bf16*)p; p += 2 * 8 * 16384 * sizeof(bf16);   // [L][8][128][128]
    bf16* WoT_a = (bf16*)p; p += 2 * 2 * 16384 * sizeof(bf16);   // [L][2][128][128]
    float* Ball = (float*)p; p += 2 * 8 * 128 * sizeof(float);   // [L][8][128]
    (void)ws_size; (void)n_in; (void)out_size;

    // ---- adjacency (edge lists are launch-constant) ----
    hipMemsetAsync(deg, 0, (size_t)N2 * sizeof(int), stream);
    int bgrid = (E + 255) / 256;
    build_adj<<<bgrid, 256, 0, stream>>>(e0, adj, deg, N, 0, E); // r2s -> dst type 1
    build_adj<<<bgrid, 256, 0, stream>>>(e1, adj, deg, 0, 1, E); // s2r -> dst type 0
    build_adj<<<bgrid, 256, 0, stream>>>(e2, adj, deg, N, 2, E); // s2s -> dst type 1

    // ---- weight prep ----
    transpose_bf16<<<32, 256, 0, stream>>>(pWr, PWrT, 64, 128, 64, 8192);
    transpose_bf16<<<16, 256, 0, stream>>>(pWs, PWsT, 32, 128, 32, 4096);
    for (int l = 0; l < 2; ++l) {
        transpose_bf16<<<128, 256, 0, stream>>>(Wq + (size_t)l * 2 * 16384,
                                                Wall + (size_t)l * 8 * 16384, 128, 128, 128, 32768);
        transpose_bf16<<<128, 256, 0, stream>>>(Wo + (size_t)l * 2 * 16384,
                                                WoT_a + (size_t)l * 2 * 16384, 128, 128, 128, 32768);
    }
    fuse_relw<<<768, 256, 0, stream>>>(Wk, Wv, Krel, Vrel, Wall);
    fuse_relb<<<8, 256, 0, stream>>>(bk, bv, bq, Krel, Vrel, Ball);

    int ggrid = (N2 * 32 + 255) / 256;

    // layer 0: fused proj + qkv (bf16 node state)
    proj_qkv<<<2 * nb0, 256, 0, stream>>>(
        x_region, x_site, PWrT, pbr, PWsT, pbs, xsb,
        Wall, Ball, q_bf, kv_bf, N, nb0);
    gather_kernel<<<ggrid, 256, 0, stream>>>(
        adj, deg, q_bf, kv_bf, prel, g_bf, N2, N);
    // layer seam: fused out(l0) + qkv(l1), bf16 state round-trip only
    out_qkv<<<2 * nb0, 256, 0, stream>>>(
        xsb, g_bf, WoT_a, bo, skip,
        Wall + (size_t)8 * 16384, Ball + 8 * 128, q_bf, kv_bf, N, nb0);
    gather_kernel<<<ggrid, 256, 0, stream>>>(
        adj, deg, q_bf, kv_bf, prel + 12, g_bf, N2, N);
    // final out (l1): blend vs bf16 prev, write fp32 d_out
    out_gemm<<<2 * nb0, 256, 0, stream>>>(
        xs, xsb, g_bf, WoT_a + (size_t)2 * 16384, bo + 2 * HD, skip + 2, N, nb0);
}